// Round 1
// baseline (1414.275 us; speedup 1.0000x reference)
//
#include <hip/hip_runtime.h>
#include <hip/hip_bf16.h>

#define D_MODEL 4096
#define NEXP    16
#define HID     688
#define HIDP    704
#define NSEL    4
#define NTOK    4096
#define LPITCH  40   // shorts per LDS row (80 bytes = 32 bf16 + 16B pad -> conflict-free)

typedef __attribute__((ext_vector_type(4))) float  f32x4;
typedef __attribute__((ext_vector_type(8))) short  bf16x8;

__device__ __forceinline__ short f2bf(float f) {
  __hip_bfloat16 h = __float2bfloat16(f);
  return __builtin_bit_cast(short, h);
}

// ---------------------------------------------------------------- zero init
__global__ void zero_meta_kernel(int* counts, float* importance) {
  const int tid = threadIdx.x;
  if (tid < NEXP) counts[tid] = 0;
  else if (tid < 2 * NEXP) importance[tid - NEXP] = 0.f;
}

__global__ void zero_y_kernel(float* __restrict__ y) {
  const size_t i = (size_t)blockIdx.x * 256 + threadIdx.x;
  *(f32x4*)(y + i * 4) = f32x4{0.f, 0.f, 0.f, 0.f};
}

// ---------------------------------------------------------------- gate
__global__ __launch_bounds__(256) void gate_kernel(
    const float* __restrict__ x, const float* __restrict__ wg,
    int* __restrict__ counts, float* __restrict__ importance,
    int* __restrict__ pair_tok, float* __restrict__ pair_scr)
{
  const int t   = blockIdx.x;
  const int tid = threadIdx.x;
  const float* xr = x + (size_t)t * D_MODEL;

  double acc[NEXP];
  #pragma unroll
  for (int e = 0; e < NEXP; ++e) acc[e] = 0.0;

  for (int i = tid; i < D_MODEL; i += 256) {
    const float xv = xr[i];
    const f32x4* w = (const f32x4*)(wg + (size_t)i * NEXP);
    #pragma unroll
    for (int q = 0; q < 4; ++q) {
      const f32x4 wv = w[q];
      #pragma unroll
      for (int j = 0; j < 4; ++j) acc[q * 4 + j] += (double)xv * (double)wv[j];
    }
  }

  #pragma unroll
  for (int e = 0; e < NEXP; ++e) {
    double v = acc[e];
    #pragma unroll
    for (int off = 32; off > 0; off >>= 1) v += __shfl_xor(v, off, 64);
    acc[e] = v;
  }

  __shared__ double red[4][NEXP];
  const int lane = tid & 63, wid = tid >> 6;
  if (lane == 0) {
    #pragma unroll
    for (int e = 0; e < NEXP; ++e) red[wid][e] = acc[e];
  }
  __syncthreads();

  if (tid == 0) {
    float lg[NEXP];
    #pragma unroll
    for (int e = 0; e < NEXP; ++e)
      lg[e] = (float)(red[0][e] + red[1][e] + red[2][e] + red[3][e]);

    int   idx[NSEL];
    float val[NSEL];
    unsigned used = 0;
    for (int k = 0; k < NSEL; ++k) {
      float best = -3.4e38f; int bi = 0;
      for (int e = 0; e < NEXP; ++e)
        if (!((used >> e) & 1u) && lg[e] > best) { best = lg[e]; bi = e; }
      idx[k] = bi; val[k] = best; used |= 1u << bi;
    }
    const float m = val[0];
    float ex[NSEL], s = 0.f;
    for (int k = 0; k < NSEL; ++k) { ex[k] = expf(val[k] - m); s += ex[k]; }
    for (int k = 0; k < NSEL; ++k) {
      const float sc = ex[k] / s;
      const int e = idx[k];
      const int pos = atomicAdd(&counts[e], 1);
      pair_tok[e * NTOK + pos] = t;
      pair_scr[e * NTOK + pos] = sc;
      atomicAdd(&importance[e], sc);
    }
  }
}

// ---------------------------------------------------------------- scan + balance loss
__global__ void scan_loss_kernel(const int* __restrict__ counts,
                                 const float* __restrict__ importance,
                                 int* __restrict__ offs, float* __restrict__ loss_out)
{
  if (threadIdx.x != 0 || blockIdx.x != 0) return;
  int   c[NEXP]; float im[NEXP];
  for (int e = 0; e < NEXP; ++e) { c[e] = counts[e]; im[e] = importance[e]; }
  int o = 0;
  for (int e = 0; e < NEXP; ++e) { offs[e] = o; o += c[e]; }
  float mi = 0.f, ml = 0.f;
  for (int e = 0; e < NEXP; ++e) { mi += im[e]; ml += (float)c[e]; }
  mi /= NEXP; ml /= NEXP;
  float vi = 0.f, vl = 0.f;
  for (int e = 0; e < NEXP; ++e) {
    vi += (im[e] - mi) * (im[e] - mi);
    vl += ((float)c[e] - ml) * ((float)c[e] - ml);
  }
  vi /= (NEXP - 1); vl /= (NEXP - 1);
  const float loss = 0.01f * (vi / (mi * mi + 1e-10f) + vl / (ml * ml + 1e-10f));
  *loss_out = loss;
}

// ---------------------------------------------------------------- stage 1: g/u GEMMs + silu*u*score -> H (bf16)
__global__ __launch_bounds__(256, 2) void stage1_kernel(
    const float* __restrict__ x, const float* __restrict__ w_g,
    const float* __restrict__ w_u, const int* __restrict__ counts,
    const int* __restrict__ offs, const int* __restrict__ pair_tok,
    const float* __restrict__ pair_scr, short* __restrict__ H)
{
  const int e   = blockIdx.z;
  const int n_e = counts[e];
  const int m0  = blockIdx.y * 128;
  if (m0 >= n_e) return;
  const int h0  = blockIdx.x * 64;

  __shared__ short ldsA[2][128 * LPITCH];
  __shared__ short ldsG[2][64 * LPITCH];
  __shared__ short ldsU[2][64 * LPITCH];

  const int tid = threadIdx.x;

  // staging: A tile 128x32 (16 f32/thread), B tiles 64x32 each (8 f32/thread)
  const int arow  = tid >> 1;
  const int ahalf = tid & 1;
  const int agr   = m0 + arow;
  const int tokA  = pair_tok[e * NTOK + (agr < n_e ? agr : 0)];
  const float* aptr = x + (size_t)tokA * D_MODEL + ahalf * 16;

  const int brow  = tid >> 2;
  const int bseg  = tid & 3;
  const bool bval = (h0 + brow) < HID;
  const int browc = bval ? (h0 + brow) : 0;
  const float* gptr = w_g + ((size_t)e * HID + browc) * D_MODEL + bseg * 8;
  const float* uptr = w_u + ((size_t)e * HID + browc) * D_MODEL + bseg * 8;

  f32x4 aR[4], gR[2], uR[2];

  auto load_tile = [&](int kt) {
    const int kb = kt * 32;
    #pragma unroll
    for (int i = 0; i < 4; ++i) aR[i] = *(const f32x4*)(aptr + kb + i * 4);
    #pragma unroll
    for (int i = 0; i < 2; ++i) gR[i] = *(const f32x4*)(gptr + kb + i * 4);
    #pragma unroll
    for (int i = 0; i < 2; ++i) uR[i] = *(const f32x4*)(uptr + kb + i * 4);
    if (!bval) {
      #pragma unroll
      for (int i = 0; i < 2; ++i) { gR[i] = f32x4{0.f,0.f,0.f,0.f}; uR[i] = f32x4{0.f,0.f,0.f,0.f}; }
    }
  };

  auto write_tile = [&](int b) {
    {
      short* p = &ldsA[b][arow * LPITCH + ahalf * 16];
      #pragma unroll
      for (int v = 0; v < 2; ++v) {
        bf16x8 tv;
        #pragma unroll
        for (int j = 0; j < 4; ++j) { tv[j] = f2bf(aR[2*v][j]); tv[4+j] = f2bf(aR[2*v+1][j]); }
        *(bf16x8*)(p + v * 8) = tv;
      }
    }
    {
      bf16x8 tv;
      #pragma unroll
      for (int j = 0; j < 4; ++j) { tv[j] = f2bf(gR[0][j]); tv[4+j] = f2bf(gR[1][j]); }
      *(bf16x8*)(&ldsG[b][brow * LPITCH + bseg * 8]) = tv;
    }
    {
      bf16x8 tv;
      #pragma unroll
      for (int j = 0; j < 4; ++j) { tv[j] = f2bf(uR[0][j]); tv[4+j] = f2bf(uR[1][j]); }
      *(bf16x8*)(&ldsU[b][brow * LPITCH + bseg * 8]) = tv;
    }
  };

  const int lane = tid & 63;
  const int wid  = tid >> 6;
  const int wm   = wid >> 1;   // 0..1 : 64 rows each
  const int wn   = wid & 1;    // 0..1 : 32 cols each
  const int fr   = lane & 15;
  const int fs   = lane >> 4;

  f32x4 accg[4][2], accu[4][2];
  #pragma unroll
  for (int fi = 0; fi < 4; ++fi)
    #pragma unroll
    for (int fj = 0; fj < 2; ++fj) {
      accg[fi][fj] = f32x4{0.f,0.f,0.f,0.f};
      accu[fi][fj] = f32x4{0.f,0.f,0.f,0.f};
    }

  auto compute_tile = [&](int b) {
    bf16x8 af[4], bg[2], bu[2];
    #pragma unroll
    for (int fi = 0; fi < 4; ++fi)
      af[fi] = *(const bf16x8*)(&ldsA[b][(wm*64 + fi*16 + fr) * LPITCH + fs*8]);
    #pragma unroll
    for (int fj = 0; fj < 2; ++fj) {
      bg[fj] = *(const bf16x8*)(&ldsG[b][(wn*32 + fj*16 + fr) * LPITCH + fs*8]);
      bu[fj] = *(const bf16x8*)(&ldsU[b][(wn*32 + fj*16 + fr) * LPITCH + fs*8]);
    }
    #pragma unroll
    for (int fi = 0; fi < 4; ++fi)
      #pragma unroll
      for (int fj = 0; fj < 2; ++fj) {
        accg[fi][fj] = __builtin_amdgcn_mfma_f32_16x16x32_bf16(af[fi], bg[fj], accg[fi][fj], 0, 0, 0);
        accu[fi][fj] = __builtin_amdgcn_mfma_f32_16x16x32_bf16(af[fi], bu[fj], accu[fi][fj], 0, 0, 0);
      }
  };

  const int KT = D_MODEL / 32;  // 128
  load_tile(0);
  write_tile(0);
  __syncthreads();
  for (int kt = 0; kt < KT; ++kt) {
    const int cur = kt & 1;
    if (kt + 1 < KT) load_tile(kt + 1);
    compute_tile(cur);
    if (kt + 1 < KT) write_tile(cur ^ 1);
    __syncthreads();
  }

  const int offs_e = offs[e];
  #pragma unroll
  for (int fi = 0; fi < 4; ++fi)
    #pragma unroll
    for (int fj = 0; fj < 2; ++fj)
      #pragma unroll
      for (int j = 0; j < 4; ++j) {
        const int r = m0 + wm*64 + fi*16 + fs*4 + j;
        if (r < n_e) {
          const int c = h0 + wn*32 + fj*16 + fr;
          const float sc = pair_scr[e * NTOK + r];
          const float g  = accg[fi][fj][j];
          const float u  = accu[fi][fj][j];
          const float hv = (g / (1.f + expf(-g))) * u * sc;
          H[(size_t)(offs_e + r) * HIDP + c] = f2bf(hv);
        }
      }
}

// ---------------------------------------------------------------- stage 2: H @ w_d^T, atomic scatter into y
__global__ __launch_bounds__(256, 2) void stage2_kernel(
    const short* __restrict__ H, const float* __restrict__ w_d,
    const int* __restrict__ counts, const int* __restrict__ offs,
    const int* __restrict__ pair_tok, float* __restrict__ y)
{
  const int e   = blockIdx.z;
  const int n_e = counts[e];
  const int m0  = blockIdx.y * 128;
  if (m0 >= n_e) return;
  const int d0  = blockIdx.x * 64;

  __shared__ short ldsA[2][128 * LPITCH];
  __shared__ short ldsB[2][64 * LPITCH];

  const int tid = threadIdx.x;
  const int arow  = tid >> 1;
  const int ahalf = tid & 1;
  const int agr   = m0 + arow;
  const int hrow  = (agr < n_e) ? (offs[e] + agr) : 0;
  const short* aptr = H + (size_t)hrow * HIDP + ahalf * 16;

  const int brow = tid >> 2;
  const int bseg = tid & 3;
  const float* bptr = w_d + ((size_t)e * D_MODEL + d0 + brow) * HID + bseg * 8;

  bf16x8 aR[2]; f32x4 bR[2];

  auto load_tile = [&](int kt) {
    const int kb = kt * 32;
    #pragma unroll
    for (int i = 0; i < 2; ++i) aR[i] = *(const bf16x8*)(aptr + kb + i * 8);
    const int kbb = kb + bseg * 8;
    if (kbb + 8 <= HID) {
      bR[0] = *(const f32x4*)(bptr + kb);
      bR[1] = *(const f32x4*)(bptr + kb + 4);
    } else {
      #pragma unroll
      for (int i = 0; i < 2; ++i)
        #pragma unroll
        for (int j = 0; j < 4; ++j)
          bR[i][j] = (kbb + i*4 + j < HID) ? bptr[kb + i*4 + j] : 0.f;
    }
  };

  auto write_tile = [&](int b) {
    short* p = &ldsA[b][arow * LPITCH + ahalf * 16];
    *(bf16x8*)(p)     = aR[0];
    *(bf16x8*)(p + 8) = aR[1];
    bf16x8 tv;
    #pragma unroll
    for (int j = 0; j < 4; ++j) { tv[j] = f2bf(bR[0][j]); tv[4+j] = f2bf(bR[1][j]); }
    *(bf16x8*)(&ldsB[b][brow * LPITCH + bseg * 8]) = tv;
  };

  const int lane = tid & 63;
  const int wid  = tid >> 6;
  const int wm   = wid >> 1;
  const int wn   = wid & 1;
  const int fr   = lane & 15;
  const int fs   = lane >> 4;

  f32x4 acc[4][2];
  #pragma unroll
  for (int fi = 0; fi < 4; ++fi)
    #pragma unroll
    for (int fj = 0; fj < 2; ++fj) acc[fi][fj] = f32x4{0.f,0.f,0.f,0.f};

  auto compute_tile = [&](int b) {
    bf16x8 af[4], bb[2];
    #pragma unroll
    for (int fi = 0; fi < 4; ++fi)
      af[fi] = *(const bf16x8*)(&ldsA[b][(wm*64 + fi*16 + fr) * LPITCH + fs*8]);
    #pragma unroll
    for (int fj = 0; fj < 2; ++fj)
      bb[fj] = *(const bf16x8*)(&ldsB[b][(wn*32 + fj*16 + fr) * LPITCH + fs*8]);
    #pragma unroll
    for (int fi = 0; fi < 4; ++fi)
      #pragma unroll
      for (int fj = 0; fj < 2; ++fj)
        acc[fi][fj] = __builtin_amdgcn_mfma_f32_16x16x32_bf16(af[fi], bb[fj], acc[fi][fj], 0, 0, 0);
  };

  const int KT = HIDP / 32;  // 22
  load_tile(0);
  write_tile(0);
  __syncthreads();
  for (int kt = 0; kt < KT; ++kt) {
    const int cur = kt & 1;
    if (kt + 1 < KT) load_tile(kt + 1);
    compute_tile(cur);
    if (kt + 1 < KT) write_tile(cur ^ 1);
    __syncthreads();
  }

  #pragma unroll
  for (int fi = 0; fi < 4; ++fi)
    #pragma unroll
    for (int j = 0; j < 4; ++j) {
      const int r = m0 + wm*64 + fi*16 + fs*4 + j;
      if (r < n_e) {
        const int tkn = pair_tok[e * NTOK + r];
        float* yr = y + (size_t)tkn * D_MODEL + d0 + wn*32 + fr;
        atomicAdd(yr,      acc[fi][0][j]);
        atomicAdd(yr + 16, acc[fi][1][j]);
      }
    }
}

// ---------------------------------------------------------------- launch
extern "C" void kernel_launch(void* const* d_in, const int* in_sizes, int n_in,
                              void* d_out, int out_size, void* d_ws, size_t ws_size,
                              hipStream_t stream) {
  const float* x     = (const float*)d_in[0];
  const float* wgate = (const float*)d_in[1];
  const float* w_g   = (const float*)d_in[2];
  const float* w_u   = (const float*)d_in[3];
  const float* w_d   = (const float*)d_in[4];

  float* y        = (float*)d_out;
  float* loss_out = y + (size_t)NTOK * D_MODEL;

  char* ws = (char*)d_ws;
  int*   counts     = (int*)ws;                                   // 16 ints
  int*   offs       = counts + 16;                                // 16 ints
  float* importance = (float*)(counts + 32);                      // 16 floats
  int*   pair_tok   = (int*)(ws + 256);                           // 16*4096 ints
  float* pair_scr   = (float*)(ws + 256 + (size_t)NEXP*NTOK*4);   // 16*4096 floats
  short* H          = (short*)(ws + 256 + (size_t)2*NEXP*NTOK*4); // 16384*704 bf16

  hipLaunchKernelGGL(zero_meta_kernel, dim3(1), dim3(64), 0, stream, counts, importance);
  hipLaunchKernelGGL(zero_y_kernel, dim3(16384), dim3(256), 0, stream, y);
  hipLaunchKernelGGL(gate_kernel, dim3(NTOK), dim3(256), 0, stream,
                     x, wgate, counts, importance, pair_tok, pair_scr);
  hipLaunchKernelGGL(scan_loss_kernel, dim3(1), dim3(64), 0, stream,
                     counts, importance, offs, loss_out);
  hipLaunchKernelGGL(stage1_kernel, dim3(HIDP / 64, NTOK / 128, NEXP), dim3(256), 0, stream,
                     x, w_g, w_u, counts, offs, pair_tok, pair_scr, H);
  hipLaunchKernelGGL(stage2_kernel, dim3(D_MODEL / 64, NTOK / 128, NEXP), dim3(256), 0, stream,
                     H, w_d, counts, offs, pair_tok, y);
}

// Round 2
// 1212.508 us; speedup vs baseline: 1.1664x; 1.1664x over previous
//
#include <hip/hip_runtime.h>
#include <hip/hip_bf16.h>

#define D_MODEL 4096
#define NEXP    16
#define HID     688
#define HIDP    704
#define NSEL    4
#define NTOK    4096
#define LPITCH  40   // fallback path LDS pitch

typedef __attribute__((ext_vector_type(4))) float  f32x4;
typedef __attribute__((ext_vector_type(8))) short  bf16x8;

__device__ __forceinline__ short f2bf(float f) {
  __hip_bfloat16 h = __float2bfloat16(f);
  return __builtin_bit_cast(short, h);
}

__device__ __forceinline__ void gload16(const void* g, void* l) {
  __builtin_amdgcn_global_load_lds(
      (const __attribute__((address_space(1))) unsigned int*)g,
      (__attribute__((address_space(3))) unsigned int*)l, 16, 0, 0);
}

// ---------------------------------------------------------------- zero init
__global__ void zero_meta_kernel(int* counts, float* importance) {
  const int tid = threadIdx.x;
  if (tid < NEXP) counts[tid] = 0;
  else if (tid < 2 * NEXP) importance[tid - NEXP] = 0.f;
}

__global__ void zero_y_kernel(float* __restrict__ y) {
  const size_t i = (size_t)blockIdx.x * 256 + threadIdx.x;
  *(f32x4*)(y + i * 4) = f32x4{0.f, 0.f, 0.f, 0.f};
}

// ---------------------------------------------------------------- gate
__global__ __launch_bounds__(256) void gate_kernel(
    const float* __restrict__ x, const float* __restrict__ wg,
    int* __restrict__ counts, float* __restrict__ importance,
    int* __restrict__ pair_tok, float* __restrict__ pair_scr)
{
  const int t   = blockIdx.x;
  const int tid = threadIdx.x;
  const float* xr = x + (size_t)t * D_MODEL;

  double acc[NEXP];
  #pragma unroll
  for (int e = 0; e < NEXP; ++e) acc[e] = 0.0;

  for (int i = tid; i < D_MODEL; i += 256) {
    const float xv = xr[i];
    const f32x4* w = (const f32x4*)(wg + (size_t)i * NEXP);
    #pragma unroll
    for (int q = 0; q < 4; ++q) {
      const f32x4 wv = w[q];
      #pragma unroll
      for (int j = 0; j < 4; ++j) acc[q * 4 + j] += (double)xv * (double)wv[j];
    }
  }

  #pragma unroll
  for (int e = 0; e < NEXP; ++e) {
    double v = acc[e];
    #pragma unroll
    for (int off = 32; off > 0; off >>= 1) v += __shfl_xor(v, off, 64);
    acc[e] = v;
  }

  __shared__ double red[4][NEXP];
  const int lane = tid & 63, wid = tid >> 6;
  if (lane == 0) {
    #pragma unroll
    for (int e = 0; e < NEXP; ++e) red[wid][e] = acc[e];
  }
  __syncthreads();

  if (tid == 0) {
    float lg[NEXP];
    #pragma unroll
    for (int e = 0; e < NEXP; ++e)
      lg[e] = (float)(red[0][e] + red[1][e] + red[2][e] + red[3][e]);

    int   idx[NSEL];
    float val[NSEL];
    unsigned used = 0;
    for (int k = 0; k < NSEL; ++k) {
      float best = -3.4e38f; int bi = 0;
      for (int e = 0; e < NEXP; ++e)
        if (!((used >> e) & 1u) && lg[e] > best) { best = lg[e]; bi = e; }
      idx[k] = bi; val[k] = best; used |= 1u << bi;
    }
    const float m = val[0];
    float ex[NSEL], s = 0.f;
    for (int k = 0; k < NSEL; ++k) { ex[k] = expf(val[k] - m); s += ex[k]; }
    for (int k = 0; k < NSEL; ++k) {
      const float sc = ex[k] / s;
      const int e = idx[k];
      const int pos = atomicAdd(&counts[e], 1);
      pair_tok[e * NTOK + pos] = t;
      pair_scr[e * NTOK + pos] = sc;
      atomicAdd(&importance[e], sc);
    }
  }
}

// ---------------------------------------------------------------- scan + balance loss
__global__ void scan_loss_kernel(const int* __restrict__ counts,
                                 const float* __restrict__ importance,
                                 int* __restrict__ offs, float* __restrict__ loss_out)
{
  if (threadIdx.x != 0 || blockIdx.x != 0) return;
  int   c[NEXP]; float im[NEXP];
  for (int e = 0; e < NEXP; ++e) { c[e] = counts[e]; im[e] = importance[e]; }
  int o = 0;
  for (int e = 0; e < NEXP; ++e) { offs[e] = o; o += c[e]; }
  float mi = 0.f, ml = 0.f;
  for (int e = 0; e < NEXP; ++e) { mi += im[e]; ml += (float)c[e]; }
  mi /= NEXP; ml /= NEXP;
  float vi = 0.f, vl = 0.f;
  for (int e = 0; e < NEXP; ++e) {
    vi += (im[e] - mi) * (im[e] - mi);
    vl += ((float)c[e] - ml) * ((float)c[e] - ml);
  }
  vi /= (NEXP - 1); vl /= (NEXP - 1);
  const float loss = 0.01f * (vi / (mi * mi + 1e-10f) + vl / (ml * ml + 1e-10f));
  *loss_out = loss;
}

// ---------------------------------------------------------------- fp32 -> bf16 conversion passes
__global__ __launch_bounds__(256) void conv_x_kernel(const float* __restrict__ src,
                                                     short* __restrict__ dst) {
  const size_t stride = (size_t)gridDim.x * 256;
  const size_t n8 = (size_t)NTOK * D_MODEL / 8;
  for (size_t i = (size_t)blockIdx.x * 256 + threadIdx.x; i < n8; i += stride) {
    const f32x4 a = *(const f32x4*)(src + i * 8);
    const f32x4 b = *(const f32x4*)(src + i * 8 + 4);
    bf16x8 o;
    #pragma unroll
    for (int j = 0; j < 4; ++j) { o[j] = f2bf(a[j]); o[4 + j] = f2bf(b[j]); }
    *(bf16x8*)(dst + i * 8) = o;
  }
}

// w_g/w_u [E][688][4096] -> padded [E][704][4096] bf16 (pad rows zero)
__global__ __launch_bounds__(256) void conv_wgu_kernel(
    const float* __restrict__ g, const float* __restrict__ u,
    short* __restrict__ gb, short* __restrict__ ub) {
  const size_t stride = (size_t)gridDim.x * 256;
  const size_t n8 = (size_t)NEXP * HIDP * (D_MODEL / 8);   // 5,767,168
  for (size_t i = (size_t)blockIdx.x * 256 + threadIdx.x; i < n8; i += stride) {
    const int c8  = (int)(i & 511);
    const int row = (int)((i >> 9) % HIDP);
    const int e   = (int)(i / (512 * HIDP));
    bf16x8 og, ou;
    if (row < HID) {
      const size_t so = ((size_t)e * HID + row) * D_MODEL + (size_t)c8 * 8;
      const f32x4 ga = *(const f32x4*)(g + so);
      const f32x4 gbv = *(const f32x4*)(g + so + 4);
      const f32x4 ua = *(const f32x4*)(u + so);
      const f32x4 ubv = *(const f32x4*)(u + so + 4);
      #pragma unroll
      for (int j = 0; j < 4; ++j) {
        og[j] = f2bf(ga[j]); og[4 + j] = f2bf(gbv[j]);
        ou[j] = f2bf(ua[j]); ou[4 + j] = f2bf(ubv[j]);
      }
    } else {
      #pragma unroll
      for (int j = 0; j < 8; ++j) { og[j] = 0; ou[j] = 0; }
    }
    *(bf16x8*)(gb + i * 8) = og;
    *(bf16x8*)(ub + i * 8) = ou;
  }
}

// w_d [E][4096][688] -> padded [E][4096][704] bf16 (pad cols zero)
__global__ __launch_bounds__(256) void conv_wd_kernel(const float* __restrict__ w,
                                                      short* __restrict__ wb) {
  const size_t stride = (size_t)gridDim.x * 256;
  const size_t n8 = (size_t)NEXP * D_MODEL * (HIDP / 8);   // 5,767,168
  for (size_t i = (size_t)blockIdx.x * 256 + threadIdx.x; i < n8; i += stride) {
    const int c8  = (int)(i % 88);
    const int row = (int)((i / 88) & (D_MODEL - 1));
    const int e   = (int)(i / (88 * D_MODEL));
    bf16x8 o;
    if (c8 < 86) {
      const size_t so = ((size_t)e * D_MODEL + row) * HID + (size_t)c8 * 8;
      const f32x4 a = *(const f32x4*)(w + so);
      const f32x4 b = *(const f32x4*)(w + so + 4);
      #pragma unroll
      for (int j = 0; j < 4; ++j) { o[j] = f2bf(a[j]); o[4 + j] = f2bf(b[j]); }
    } else {
      #pragma unroll
      for (int j = 0; j < 8; ++j) o[j] = 0;
    }
    *(bf16x8*)(wb + i * 8) = o;
  }
}

// ================================================================ bf16 fast path
// stage1b: BM=128, BN=64(g)+64(u), BK=64, global_load_lds, XOR-swizzled LDS.
// Grid 5632 linear; XCD-colocating decode: blocks sharing (e, m-tile) land on
// one XCD consecutively (A-tile stays in that XCD's L2).
__global__ __launch_bounds__(256, 2) void stage1b_kernel(
    const short* __restrict__ xb, const short* __restrict__ wgb,
    const short* __restrict__ wub, const int* __restrict__ counts,
    const int* __restrict__ offs, const int* __restrict__ pair_tok,
    const float* __restrict__ pair_scr, short* __restrict__ H)
{
  const int bid = blockIdx.x;
  const int xcd = bid & 7;
  const int sq  = bid >> 3;           // 0..703
  const int ht  = sq % 11;
  const int p   = (sq / 11) * 8 + xcd; // 0..511
  const int mt  = p & 31;
  const int e   = p >> 5;

  const int n_e = counts[e];
  const int m0  = mt * 128;
  if (m0 >= n_e) return;
  const int h0  = ht * 64;

  __shared__ short ldsA[2][128 * 64];
  __shared__ short ldsG[2][64 * 64];
  __shared__ short ldsU[2][64 * 64];

  const int tid  = threadIdx.x;
  const int lane = tid & 63;
  const int wid  = tid >> 6;

  // per-thread staging sources (pre-swizzled global addresses; LDS dest linear)
  const short* srcA[4]; const short* srcG[2]; const short* srcU[2];
  #pragma unroll
  for (int i = 0; i < 4; ++i) {
    const int c    = wid * 4 + i;             // A chunk 0..15 (8 rows each)
    const int row  = 8 * c + (lane >> 3);
    const int slot = (lane & 7) ^ (row & 7);
    int r = m0 + row; if (r >= n_e) r = n_e - 1;
    const int tok = pair_tok[e * NTOK + r];
    srcA[i] = xb + (size_t)tok * D_MODEL + slot * 8;
  }
  #pragma unroll
  for (int i = 0; i < 2; ++i) {
    const int c    = wid * 2 + i;             // B chunk 0..7
    const int row  = 8 * c + (lane >> 3);
    const int slot = (lane & 7) ^ (row & 7);
    const size_t rb = ((size_t)e * HIDP + h0 + row) * D_MODEL + slot * 8;
    srcG[i] = wgb + rb;
    srcU[i] = wub + rb;
  }

  const int wm = wid >> 1, wn = wid & 1;
  const int fr = lane & 15, fs = lane >> 4;

  f32x4 accg[4][2], accu[4][2];
  #pragma unroll
  for (int fi = 0; fi < 4; ++fi)
    #pragma unroll
    for (int fj = 0; fj < 2; ++fj) {
      accg[fi][fj] = f32x4{0.f, 0.f, 0.f, 0.f};
      accu[fi][fj] = f32x4{0.f, 0.f, 0.f, 0.f};
    }

  auto stage = [&](int kt, int b) {
    const int ko = kt * 64;
    #pragma unroll
    for (int i = 0; i < 4; ++i)
      gload16(srcA[i] + ko, &ldsA[b][(wid * 4 + i) * 512]);
    #pragma unroll
    for (int i = 0; i < 2; ++i) {
      gload16(srcG[i] + ko, &ldsG[b][(wid * 2 + i) * 512]);
      gload16(srcU[i] + ko, &ldsU[b][(wid * 2 + i) * 512]);
    }
  };

  auto compute = [&](int b) {
    const short* Ab = ldsA[b]; const short* Gb = ldsG[b]; const short* Ub = ldsU[b];
    #pragma unroll
    for (int h = 0; h < 2; ++h) {
      const int so = ((h * 4 + fs) ^ (fr & 7)) * 8;
      bf16x8 af[4], bg[2], bu[2];
      #pragma unroll
      for (int fi = 0; fi < 4; ++fi)
        af[fi] = *(const bf16x8*)&Ab[(wm * 64 + fi * 16 + fr) * 64 + so];
      #pragma unroll
      for (int fj = 0; fj < 2; ++fj) {
        bg[fj] = *(const bf16x8*)&Gb[(wn * 32 + fj * 16 + fr) * 64 + so];
        bu[fj] = *(const bf16x8*)&Ub[(wn * 32 + fj * 16 + fr) * 64 + so];
      }
      #pragma unroll
      for (int fi = 0; fi < 4; ++fi)
        #pragma unroll
        for (int fj = 0; fj < 2; ++fj) {
          accg[fi][fj] = __builtin_amdgcn_mfma_f32_16x16x32_bf16(af[fi], bg[fj], accg[fi][fj], 0, 0, 0);
          accu[fi][fj] = __builtin_amdgcn_mfma_f32_16x16x32_bf16(af[fi], bu[fj], accu[fi][fj], 0, 0, 0);
        }
    }
  };

  const int KT = D_MODEL / 64;  // 64
  stage(0, 0);
  for (int kt = 0; kt < KT; ++kt) {
    const int cur = kt & 1;
    __syncthreads();                       // drains stage(kt) vmcnt
    if (kt + 1 < KT) stage(kt + 1, cur ^ 1);
    compute(cur);
  }

  const int offs_e = offs[e];
  #pragma unroll
  for (int fi = 0; fi < 4; ++fi)
    #pragma unroll
    for (int fj = 0; fj < 2; ++fj)
      #pragma unroll
      for (int j = 0; j < 4; ++j) {
        const int r = m0 + wm * 64 + fi * 16 + fs * 4 + j;
        if (r < n_e) {
          const int c = h0 + wn * 32 + fj * 16 + fr;
          const float sc = pair_scr[e * NTOK + r];
          const float g  = accg[fi][fj][j];
          const float u  = accu[fi][fj][j];
          const float hv = (g / (1.f + expf(-g))) * u * sc;
          H[(size_t)(offs_e + r) * HIDP + c] = f2bf(hv);
        }
      }
}

// stage2b: BM=128, BN=128, BK=64 over K=704 (11 steps); atomic scatter to y.
__global__ __launch_bounds__(256, 2) void stage2b_kernel(
    const short* __restrict__ H, const short* __restrict__ wdb,
    const int* __restrict__ counts, const int* __restrict__ offs,
    const int* __restrict__ pair_tok, float* __restrict__ y)
{
  const int bid = blockIdx.x;
  const int xcd = bid & 7;
  const int sq  = bid >> 3;            // 0..2047
  const int dt  = sq & 31;
  const int p   = (sq >> 5) * 8 + xcd; // 0..511
  const int mt  = p & 31;
  const int e   = p >> 5;

  const int n_e = counts[e];
  const int m0  = mt * 128;
  if (m0 >= n_e) return;
  const int d0  = dt * 128;

  __shared__ short ldsA[2][128 * 64];
  __shared__ short ldsB[2][128 * 64];

  const int tid  = threadIdx.x;
  const int lane = tid & 63;
  const int wid  = tid >> 6;
  const int offs_e = offs[e];

  const short* srcA[4]; const short* srcB[4];
  #pragma unroll
  for (int i = 0; i < 4; ++i) {
    const int c    = wid * 4 + i;
    const int row  = 8 * c + (lane >> 3);
    const int slot = (lane & 7) ^ (row & 7);
    int r = m0 + row; if (r >= n_e) r = n_e - 1;
    srcA[i] = H + (size_t)(offs_e + r) * HIDP + slot * 8;
    srcB[i] = wdb + ((size_t)e * D_MODEL + d0 + row) * HIDP + slot * 8;
  }

  const int wm = wid >> 1, wn = wid & 1;
  const int fr = lane & 15, fs = lane >> 4;

  f32x4 acc[4][4];
  #pragma unroll
  for (int fi = 0; fi < 4; ++fi)
    #pragma unroll
    for (int fj = 0; fj < 4; ++fj) acc[fi][fj] = f32x4{0.f, 0.f, 0.f, 0.f};

  auto stage = [&](int kt, int b) {
    const int ko = kt * 64;
    #pragma unroll
    for (int i = 0; i < 4; ++i) {
      gload16(srcA[i] + ko, &ldsA[b][(wid * 4 + i) * 512]);
      gload16(srcB[i] + ko, &ldsB[b][(wid * 4 + i) * 512]);
    }
  };

  auto compute = [&](int b) {
    const short* Ab = ldsA[b]; const short* Bb = ldsB[b];
    #pragma unroll
    for (int h = 0; h < 2; ++h) {
      const int so = ((h * 4 + fs) ^ (fr & 7)) * 8;
      bf16x8 af[4], bb[4];
      #pragma unroll
      for (int fi = 0; fi < 4; ++fi)
        af[fi] = *(const bf16x8*)&Ab[(wm * 64 + fi * 16 + fr) * 64 + so];
      #pragma unroll
      for (int fj = 0; fj < 4; ++fj)
        bb[fj] = *(const bf16x8*)&Bb[(wn * 64 + fj * 16 + fr) * 64 + so];
      #pragma unroll
      for (int fi = 0; fi < 4; ++fi)
        #pragma unroll
        for (int fj = 0; fj < 4; ++fj)
          acc[fi][fj] = __builtin_amdgcn_mfma_f32_16x16x32_bf16(af[fi], bb[fj], acc[fi][fj], 0, 0, 0);
    }
  };

  const int KT = HIDP / 64;  // 11
  stage(0, 0);
  for (int kt = 0; kt < KT; ++kt) {
    const int cur = kt & 1;
    __syncthreads();
    if (kt + 1 < KT) stage(kt + 1, cur ^ 1);
    compute(cur);
  }

  #pragma unroll
  for (int fi = 0; fi < 4; ++fi)
    #pragma unroll
    for (int j = 0; j < 4; ++j) {
      const int r = m0 + wm * 64 + fi * 16 + fs * 4 + j;
      if (r < n_e) {
        const int tok = pair_tok[e * NTOK + r];
        float* yr = y + (size_t)tok * D_MODEL + d0 + wn * 64 + fr;
        #pragma unroll
        for (int fj = 0; fj < 4; ++fj)
          atomicAdd(yr + fj * 16, acc[fi][fj][j]);
      }
    }
}

// ================================================================ fallback path (round-1 kernels, occupancy bumped)
__global__ __launch_bounds__(256, 4) void stage1_fb(
    const float* __restrict__ x, const float* __restrict__ w_g,
    const float* __restrict__ w_u, const int* __restrict__ counts,
    const int* __restrict__ offs, const int* __restrict__ pair_tok,
    const float* __restrict__ pair_scr, short* __restrict__ H)
{
  const int e   = blockIdx.z;
  const int n_e = counts[e];
  const int m0  = blockIdx.y * 128;
  if (m0 >= n_e) return;
  const int h0  = blockIdx.x * 64;

  __shared__ short ldsA[2][128 * LPITCH];
  __shared__ short ldsG[2][64 * LPITCH];
  __shared__ short ldsU[2][64 * LPITCH];

  const int tid = threadIdx.x;
  const int arow  = tid >> 1;
  const int ahalf = tid & 1;
  const int agr   = m0 + arow;
  const int tokA  = pair_tok[e * NTOK + (agr < n_e ? agr : 0)];
  const float* aptr = x + (size_t)tokA * D_MODEL + ahalf * 16;

  const int brow  = tid >> 2;
  const int bseg  = tid & 3;
  const bool bval = (h0 + brow) < HID;
  const int browc = bval ? (h0 + brow) : 0;
  const float* gptr = w_g + ((size_t)e * HID + browc) * D_MODEL + bseg * 8;
  const float* uptr = w_u + ((size_t)e * HID + browc) * D_MODEL + bseg * 8;

  f32x4 aR[4], gR[2], uR[2];

  auto load_tile = [&](int kt) {
    const int kb = kt * 32;
    #pragma unroll
    for (int i = 0; i < 4; ++i) aR[i] = *(const f32x4*)(aptr + kb + i * 4);
    #pragma unroll
    for (int i = 0; i < 2; ++i) gR[i] = *(const f32x4*)(gptr + kb + i * 4);
    #pragma unroll
    for (int i = 0; i < 2; ++i) uR[i] = *(const f32x4*)(uptr + kb + i * 4);
    if (!bval) {
      #pragma unroll
      for (int i = 0; i < 2; ++i) { gR[i] = f32x4{0.f,0.f,0.f,0.f}; uR[i] = f32x4{0.f,0.f,0.f,0.f}; }
    }
  };

  auto write_tile = [&](int b) {
    short* pA = &ldsA[b][arow * LPITCH + ahalf * 16];
    #pragma unroll
    for (int v = 0; v < 2; ++v) {
      bf16x8 tv;
      #pragma unroll
      for (int j = 0; j < 4; ++j) { tv[j] = f2bf(aR[2*v][j]); tv[4+j] = f2bf(aR[2*v+1][j]); }
      *(bf16x8*)(pA + v * 8) = tv;
    }
    bf16x8 tg, tu;
    #pragma unroll
    for (int j = 0; j < 4; ++j) { tg[j] = f2bf(gR[0][j]); tg[4+j] = f2bf(gR[1][j]); }
    #pragma unroll
    for (int j = 0; j < 4; ++j) { tu[j] = f2bf(uR[0][j]); tu[4+j] = f2bf(uR[1][j]); }
    *(bf16x8*)(&ldsG[b][brow * LPITCH + bseg * 8]) = tg;
    *(bf16x8*)(&ldsU[b][brow * LPITCH + bseg * 8]) = tu;
  };

  const int lane = tid & 63;
  const int wid  = tid >> 6;
  const int wm   = wid >> 1;
  const int wn   = wid & 1;
  const int fr   = lane & 15;
  const int fs   = lane >> 4;

  f32x4 accg[4][2], accu[4][2];
  #pragma unroll
  for (int fi = 0; fi < 4; ++fi)
    #pragma unroll
    for (int fj = 0; fj < 2; ++fj) {
      accg[fi][fj] = f32x4{0.f,0.f,0.f,0.f};
      accu[fi][fj] = f32x4{0.f,0.f,0.f,0.f};
    }

  auto compute_tile = [&](int b) {
    bf16x8 af[4], bg[2], bu[2];
    #pragma unroll
    for (int fi = 0; fi < 4; ++fi)
      af[fi] = *(const bf16x8*)(&ldsA[b][(wm*64 + fi*16 + fr) * LPITCH + fs*8]);
    #pragma unroll
    for (int fj = 0; fj < 2; ++fj) {
      bg[fj] = *(const bf16x8*)(&ldsG[b][(wn*32 + fj*16 + fr) * LPITCH + fs*8]);
      bu[fj] = *(const bf16x8*)(&ldsU[b][(wn*32 + fj*16 + fr) * LPITCH + fs*8]);
    }
    #pragma unroll
    for (int fi = 0; fi < 4; ++fi)
      #pragma unroll
      for (int fj = 0; fj < 2; ++fj) {
        accg[fi][fj] = __builtin_amdgcn_mfma_f32_16x16x32_bf16(af[fi], bg[fj], accg[fi][fj], 0, 0, 0);
        accu[fi][fj] = __builtin_amdgcn_mfma_f32_16x16x32_bf16(af[fi], bu[fj], accu[fi][fj], 0, 0, 0);
      }
  };

  const int KT = D_MODEL / 32;
  load_tile(0);
  write_tile(0);
  __syncthreads();
  for (int kt = 0; kt < KT; ++kt) {
    const int cur = kt & 1;
    if (kt + 1 < KT) load_tile(kt + 1);
    compute_tile(cur);
    if (kt + 1 < KT) write_tile(cur ^ 1);
    __syncthreads();
  }

  const int offs_e = offs[e];
  #pragma unroll
  for (int fi = 0; fi < 4; ++fi)
    #pragma unroll
    for (int fj = 0; fj < 2; ++fj)
      #pragma unroll
      for (int j = 0; j < 4; ++j) {
        const int r = m0 + wm*64 + fi*16 + fs*4 + j;
        if (r < n_e) {
          const int c = h0 + wn*32 + fj*16 + fr;
          const float sc = pair_scr[e * NTOK + r];
          const float g  = accg[fi][fj][j];
          const float u  = accu[fi][fj][j];
          const float hv = (g / (1.f + expf(-g))) * u * sc;
          H[(size_t)(offs_e + r) * HIDP + c] = f2bf(hv);
        }
      }
}

__global__ __launch_bounds__(256, 4) void stage2_fb(
    const short* __restrict__ H, const float* __restrict__ w_d,
    const int* __restrict__ counts, const int* __restrict__ offs,
    const int* __restrict__ pair_tok, float* __restrict__ y)
{
  const int e   = blockIdx.z;
  const int n_e = counts[e];
  const int m0  = blockIdx.y * 128;
  if (m0 >= n_e) return;
  const int d0  = blockIdx.x * 64;

  __shared__ short ldsA[2][128 * LPITCH];
  __shared__ short ldsB[2][64 * LPITCH];

  const int tid = threadIdx.x;
  const int arow  = tid >> 1;
  const int ahalf = tid & 1;
  const int agr   = m0 + arow;
  const int hrow  = (agr < n_e) ? (offs[e] + agr) : 0;
  const short* aptr = H + (size_t)hrow * HIDP + ahalf * 16;

  const int brow = tid >> 2;
  const int bseg = tid & 3;
  const float* bptr = w_d + ((size_t)e * D_MODEL + d0 + brow) * HID + bseg * 8;

  bf16x8 aR[2]; f32x4 bR[2];

  auto load_tile = [&](int kt) {
    const int kb = kt * 32;
    #pragma unroll
    for (int i = 0; i < 2; ++i) aR[i] = *(const bf16x8*)(aptr + kb + i * 8);
    const int kbb = kb + bseg * 8;
    if (kbb + 8 <= HID) {
      bR[0] = *(const f32x4*)(bptr + kb);
      bR[1] = *(const f32x4*)(bptr + kb + 4);
    } else {
      #pragma unroll
      for (int i = 0; i < 2; ++i)
        #pragma unroll
        for (int j = 0; j < 4; ++j)
          bR[i][j] = (kbb + i*4 + j < HID) ? bptr[kb + i*4 + j] : 0.f;
    }
  };

  auto write_tile = [&](int b) {
    short* p = &ldsA[b][arow * LPITCH + ahalf * 16];
    *(bf16x8*)(p)     = aR[0];
    *(bf16x8*)(p + 8) = aR[1];
    bf16x8 tv;
    #pragma unroll
    for (int j = 0; j < 4; ++j) { tv[j] = f2bf(bR[0][j]); tv[4+j] = f2bf(bR[1][j]); }
    *(bf16x8*)(&ldsB[b][brow * LPITCH + bseg * 8]) = tv;
  };

  const int lane = tid & 63;
  const int wid  = tid >> 6;
  const int wm   = wid >> 1;
  const int wn   = wid & 1;
  const int fr   = lane & 15;
  const int fs   = lane >> 4;

  f32x4 acc[4][2];
  #pragma unroll
  for (int fi = 0; fi < 4; ++fi)
    #pragma unroll
    for (int fj = 0; fj < 2; ++fj) acc[fi][fj] = f32x4{0.f,0.f,0.f,0.f};

  auto compute_tile = [&](int b) {
    bf16x8 af[4], bb[2];
    #pragma unroll
    for (int fi = 0; fi < 4; ++fi)
      af[fi] = *(const bf16x8*)(&ldsA[b][(wm*64 + fi*16 + fr) * LPITCH + fs*8]);
    #pragma unroll
    for (int fj = 0; fj < 2; ++fj)
      bb[fj] = *(const bf16x8*)(&ldsB[b][(wn*32 + fj*16 + fr) * LPITCH + fs*8]);
    #pragma unroll
    for (int fi = 0; fi < 4; ++fi)
      #pragma unroll
      for (int fj = 0; fj < 2; ++fj)
        acc[fi][fj] = __builtin_amdgcn_mfma_f32_16x16x32_bf16(af[fi], bb[fj], acc[fi][fj], 0, 0, 0);
  };

  const int KT = HIDP / 32;
  load_tile(0);
  write_tile(0);
  __syncthreads();
  for (int kt = 0; kt < KT; ++kt) {
    const int cur = kt & 1;
    if (kt + 1 < KT) load_tile(kt + 1);
    compute_tile(cur);
    if (kt + 1 < KT) write_tile(cur ^ 1);
    __syncthreads();
  }

  #pragma unroll
  for (int fi = 0; fi < 4; ++fi)
    #pragma unroll
    for (int j = 0; j < 4; ++j) {
      const int r = m0 + wm*64 + fi*16 + fs*4 + j;
      if (r < n_e) {
        const int tkn = pair_tok[e * NTOK + r];
        float* yr = y + (size_t)tkn * D_MODEL + d0 + wn*32 + fr;
        atomicAdd(yr,      acc[fi][0][j]);
        atomicAdd(yr + 16, acc[fi][1][j]);
      }
    }
}

// ---------------------------------------------------------------- launch
extern "C" void kernel_launch(void* const* d_in, const int* in_sizes, int n_in,
                              void* d_out, int out_size, void* d_ws, size_t ws_size,
                              hipStream_t stream) {
  const float* x     = (const float*)d_in[0];
  const float* wgate = (const float*)d_in[1];
  const float* w_g   = (const float*)d_in[2];
  const float* w_u   = (const float*)d_in[3];
  const float* w_d   = (const float*)d_in[4];

  float* y        = (float*)d_out;
  float* loss_out = y + (size_t)NTOK * D_MODEL;

  char* ws = (char*)d_ws;
  int*   counts     = (int*)ws;
  int*   offs       = counts + 16;
  float* importance = (float*)(counts + 32);
  int*   pair_tok   = (int*)(ws + 256);
  float* pair_scr   = (float*)(ws + 256 + (size_t)NEXP * NTOK * 4);
  short* H          = (short*)(ws + 256 + (size_t)2 * NEXP * NTOK * 4);   // 524544

  const size_t H_BYTES   = (size_t)NTOK * NSEL * HIDP * 2;        // 23,068,672
  const size_t XB_BYTES  = (size_t)NTOK * D_MODEL * 2;            // 33,554,432
  const size_t WB_BYTES  = (size_t)NEXP * HIDP * D_MODEL * 2;     // 92,274,688
  short* xbuf = (short*)((char*)H + H_BYTES);
  short* wgb  = xbuf + (size_t)NTOK * D_MODEL;
  short* wub  = wgb + (size_t)NEXP * HIDP * D_MODEL;
  short* wdb  = wub + (size_t)NEXP * HIDP * D_MODEL;
  const size_t NEED = 524544 + H_BYTES + XB_BYTES + 3 * WB_BYTES; // ~334 MB
  const bool big = ws_size >= NEED;

  hipLaunchKernelGGL(zero_meta_kernel, dim3(1), dim3(64), 0, stream, counts, importance);
  hipLaunchKernelGGL(zero_y_kernel, dim3(16384), dim3(256), 0, stream, y);
  hipLaunchKernelGGL(gate_kernel, dim3(NTOK), dim3(256), 0, stream,
                     x, wgate, counts, importance, pair_tok, pair_scr);
  hipLaunchKernelGGL(scan_loss_kernel, dim3(1), dim3(64), 0, stream,
                     counts, importance, offs, loss_out);

  if (big) {
    hipLaunchKernelGGL(conv_x_kernel,   dim3(2048), dim3(256), 0, stream, x, xbuf);
    hipLaunchKernelGGL(conv_wgu_kernel, dim3(4096), dim3(256), 0, stream, w_g, w_u, wgb, wub);
    hipLaunchKernelGGL(conv_wd_kernel,  dim3(4096), dim3(256), 0, stream, w_d, wdb);
    hipLaunchKernelGGL(stage1b_kernel, dim3(5632), dim3(256), 0, stream,
                       xbuf, wgb, wub, counts, offs, pair_tok, pair_scr, H);
    hipLaunchKernelGGL(stage2b_kernel, dim3(16384), dim3(256), 0, stream,
                       H, wdb, counts, offs, pair_tok, y);
  } else {
    hipLaunchKernelGGL(stage1_fb, dim3(HIDP / 64, NTOK / 128, NEXP), dim3(256), 0, stream,
                       x, w_g, w_u, counts, offs, pair_tok, pair_scr, H);
    hipLaunchKernelGGL(stage2_fb, dim3(D_MODEL / 64, NTOK / 128, NEXP), dim3(256), 0, stream,
                       H, w_d, counts, offs, pair_tok, y);
  }
}

// Round 3
// 1027.464 us; speedup vs baseline: 1.3765x; 1.1801x over previous
//
#include <hip/hip_runtime.h>
#include <hip/hip_bf16.h>

#define D_MODEL 4096
#define NEXP    16
#define HID     688
#define HIDP    704
#define NSEL    4
#define NTOK    4096

typedef __attribute__((ext_vector_type(4))) float  f32x4;
typedef __attribute__((ext_vector_type(8))) short  bf16x8;

__device__ __forceinline__ short f2bf(float f) {
  __hip_bfloat16 h = __float2bfloat16(f);
  return __builtin_bit_cast(short, h);
}

__device__ __forceinline__ void gload16(const void* g, void* l) {
  __builtin_amdgcn_global_load_lds(
      (const __attribute__((address_space(1))) unsigned int*)g,
      (__attribute__((address_space(3))) unsigned int*)l, 16, 0, 0);
}

// ---------------------------------------------------------------- zero init
__global__ void zero_meta_kernel(int* counts, float* importance) {
  const int tid = threadIdx.x;
  if (tid < NEXP) counts[tid] = 0;
  else if (tid < 2 * NEXP) importance[tid - NEXP] = 0.f;
}

__global__ void zero_y_kernel(float* __restrict__ y) {
  const size_t i = (size_t)blockIdx.x * 256 + threadIdx.x;
  *(f32x4*)(y + i * 4) = f32x4{0.f, 0.f, 0.f, 0.f};
}

// ---------------------------------------------------------------- gate
__global__ __launch_bounds__(256) void gate_kernel(
    const float* __restrict__ x, const float* __restrict__ wg,
    int* __restrict__ counts, float* __restrict__ importance,
    int* __restrict__ pair_tok, float* __restrict__ pair_scr)
{
  const int t   = blockIdx.x;
  const int tid = threadIdx.x;
  const float* xr = x + (size_t)t * D_MODEL;

  double acc[NEXP];
  #pragma unroll
  for (int e = 0; e < NEXP; ++e) acc[e] = 0.0;

  for (int i = tid; i < D_MODEL; i += 256) {
    const float xv = xr[i];
    const f32x4* w = (const f32x4*)(wg + (size_t)i * NEXP);
    #pragma unroll
    for (int q = 0; q < 4; ++q) {
      const f32x4 wv = w[q];
      #pragma unroll
      for (int j = 0; j < 4; ++j) acc[q * 4 + j] += (double)xv * (double)wv[j];
    }
  }

  #pragma unroll
  for (int e = 0; e < NEXP; ++e) {
    double v = acc[e];
    #pragma unroll
    for (int off = 32; off > 0; off >>= 1) v += __shfl_xor(v, off, 64);
    acc[e] = v;
  }

  __shared__ double red[4][NEXP];
  const int lane = tid & 63, wid = tid >> 6;
  if (lane == 0) {
    #pragma unroll
    for (int e = 0; e < NEXP; ++e) red[wid][e] = acc[e];
  }
  __syncthreads();

  if (tid == 0) {
    float lg[NEXP];
    #pragma unroll
    for (int e = 0; e < NEXP; ++e)
      lg[e] = (float)(red[0][e] + red[1][e] + red[2][e] + red[3][e]);

    int   idx[NSEL];
    float val[NSEL];
    unsigned used = 0;
    for (int k = 0; k < NSEL; ++k) {
      float best = -3.4e38f; int bi = 0;
      for (int e = 0; e < NEXP; ++e)
        if (!((used >> e) & 1u) && lg[e] > best) { best = lg[e]; bi = e; }
      idx[k] = bi; val[k] = best; used |= 1u << bi;
    }
    const float m = val[0];
    float ex[NSEL], s = 0.f;
    for (int k = 0; k < NSEL; ++k) { ex[k] = expf(val[k] - m); s += ex[k]; }
    for (int k = 0; k < NSEL; ++k) {
      const float sc = ex[k] / s;
      const int e = idx[k];
      const int pos = atomicAdd(&counts[e], 1);
      pair_tok[e * NTOK + pos] = t;
      pair_scr[e * NTOK + pos] = sc;
      atomicAdd(&importance[e], sc);
    }
  }
}

// ---------------------------------------------------------------- scan + balance loss
__global__ void scan_loss_kernel(const int* __restrict__ counts,
                                 const float* __restrict__ importance,
                                 int* __restrict__ offs, float* __restrict__ loss_out)
{
  if (threadIdx.x != 0 || blockIdx.x != 0) return;
  int   c[NEXP]; float im[NEXP];
  for (int e = 0; e < NEXP; ++e) { c[e] = counts[e]; im[e] = importance[e]; }
  int o = 0;
  for (int e = 0; e < NEXP; ++e) { offs[e] = o; o += c[e]; }
  float mi = 0.f, ml = 0.f;
  for (int e = 0; e < NEXP; ++e) { mi += im[e]; ml += (float)c[e]; }
  mi /= NEXP; ml /= NEXP;
  float vi = 0.f, vl = 0.f;
  for (int e = 0; e < NEXP; ++e) {
    vi += (im[e] - mi) * (im[e] - mi);
    vl += ((float)c[e] - ml) * ((float)c[e] - ml);
  }
  vi /= (NEXP - 1); vl /= (NEXP - 1);
  const float loss = 0.01f * (vi / (mi * mi + 1e-10f) + vl / (ml * ml + 1e-10f));
  *loss_out = loss;
}

// ---------------------------------------------------------------- fp32 -> bf16 conversion passes
__global__ __launch_bounds__(256) void conv_x_kernel(const float* __restrict__ src,
                                                     short* __restrict__ dst) {
  const size_t stride = (size_t)gridDim.x * 256;
  const size_t n8 = (size_t)NTOK * D_MODEL / 8;
  for (size_t i = (size_t)blockIdx.x * 256 + threadIdx.x; i < n8; i += stride) {
    const f32x4 a = *(const f32x4*)(src + i * 8);
    const f32x4 b = *(const f32x4*)(src + i * 8 + 4);
    bf16x8 o;
    #pragma unroll
    for (int j = 0; j < 4; ++j) { o[j] = f2bf(a[j]); o[4 + j] = f2bf(b[j]); }
    *(bf16x8*)(dst + i * 8) = o;
  }
}

// w_g/w_u [E][688][4096] -> padded [E][704][4096] bf16 (pad rows zero)
__global__ __launch_bounds__(256) void conv_wgu_kernel(
    const float* __restrict__ g, const float* __restrict__ u,
    short* __restrict__ gb, short* __restrict__ ub) {
  const size_t stride = (size_t)gridDim.x * 256;
  const size_t n8 = (size_t)NEXP * HIDP * (D_MODEL / 8);
  for (size_t i = (size_t)blockIdx.x * 256 + threadIdx.x; i < n8; i += stride) {
    const int c8  = (int)(i & 511);
    const int row = (int)((i >> 9) % HIDP);
    const int e   = (int)(i / (512 * HIDP));
    bf16x8 og, ou;
    if (row < HID) {
      const size_t so = ((size_t)e * HID + row) * D_MODEL + (size_t)c8 * 8;
      const f32x4 ga = *(const f32x4*)(g + so);
      const f32x4 gbv = *(const f32x4*)(g + so + 4);
      const f32x4 ua = *(const f32x4*)(u + so);
      const f32x4 ubv = *(const f32x4*)(u + so + 4);
      #pragma unroll
      for (int j = 0; j < 4; ++j) {
        og[j] = f2bf(ga[j]); og[4 + j] = f2bf(gbv[j]);
        ou[j] = f2bf(ua[j]); ou[4 + j] = f2bf(ubv[j]);
      }
    } else {
      #pragma unroll
      for (int j = 0; j < 8; ++j) { og[j] = 0; ou[j] = 0; }
    }
    *(bf16x8*)(gb + i * 8) = og;
    *(bf16x8*)(ub + i * 8) = ou;
  }
}

// w_d [E][4096][688] -> padded [E][4096][704] bf16 (pad cols zero)
__global__ __launch_bounds__(256) void conv_wd_kernel(const float* __restrict__ w,
                                                      short* __restrict__ wb) {
  const size_t stride = (size_t)gridDim.x * 256;
  const size_t n8 = (size_t)NEXP * D_MODEL * (HIDP / 8);
  for (size_t i = (size_t)blockIdx.x * 256 + threadIdx.x; i < n8; i += stride) {
    const int c8  = (int)(i % 88);
    const int row = (int)((i / 88) & (D_MODEL - 1));
    const int e   = (int)(i / (88 * D_MODEL));
    bf16x8 o;
    if (c8 < 86) {
      const size_t so = ((size_t)e * D_MODEL + row) * HID + (size_t)c8 * 8;
      const f32x4 a = *(const f32x4*)(w + so);
      const f32x4 b = *(const f32x4*)(w + so + 4);
      #pragma unroll
      for (int j = 0; j < 4; ++j) { o[j] = f2bf(a[j]); o[4 + j] = f2bf(b[j]); }
    } else {
      #pragma unroll
      for (int j = 0; j < 8; ++j) o[j] = 0;
    }
    *(bf16x8*)(wb + i * 8) = o;
  }
}

// ================================================================ stage 1
// BM=128, BN=64(g)+64(u), BK=32 double-buffered (32 KiB LDS -> 5 blocks/CU).
// Grid 11*512: ht outermost (weights stream once; all (e,mt) of one ht are
// concurrent), experts pinned 2-per-XCD so weight panels live in that L2.
__global__ __launch_bounds__(256, 4) void stage1b_kernel(
    const short* __restrict__ xb, const short* __restrict__ wgb,
    const short* __restrict__ wub, const int* __restrict__ counts,
    const int* __restrict__ offs, const int* __restrict__ pair_tok,
    const float* __restrict__ pair_scr, short* __restrict__ H)
{
  const int bid = blockIdx.x;
  const int ht  = bid >> 9;            // 0..10  (slowest)
  const int q   = bid & 511;
  const int xcd = q & 7;
  const int idx = q >> 3;              // 0..63
  const int e   = xcd * 2 + (idx & 1);
  const int mt  = idx >> 1;            // 0..31

  const int n_e = counts[e];
  const int m0  = mt * 128;
  if (m0 >= n_e) return;
  const int h0  = ht * 64;

  __shared__ short ldsA[2][128 * 32];
  __shared__ short ldsG[2][64 * 32];
  __shared__ short ldsU[2][64 * 32];

  const int tid  = threadIdx.x;
  const int lane = tid & 63;
  const int wid  = tid >> 6;

  // staging sources: pre-swizzled global addresses, linear LDS dest.
  // chunk = 16 rows x 32 cols (1024 B); row-in-chunk = lane>>2, slot = lane&3,
  // swizzle slot ^= row&3  (4 slots of 16B per 64B row).
  const short* srcA[2]; const short* srcG; const short* srcU;
  #pragma unroll
  for (int i = 0; i < 2; ++i) {
    const int c    = wid * 2 + i;              // 0..7
    const int row  = 16 * c + (lane >> 2);     // 0..127
    const int slot = (lane & 3) ^ (row & 3);
    int r = m0 + row; if (r >= n_e) r = n_e - 1;
    const int tok = pair_tok[e * NTOK + r];
    srcA[i] = xb + (size_t)tok * D_MODEL + slot * 8;
  }
  {
    const int c    = wid;                      // 0..3
    const int row  = 16 * c + (lane >> 2);     // 0..63
    const int slot = (lane & 3) ^ (row & 3);
    const size_t rb = ((size_t)e * HIDP + h0 + row) * D_MODEL + slot * 8;
    srcG = wgb + rb;
    srcU = wub + rb;
  }

  const int wm = wid >> 1, wn = wid & 1;
  const int fr = lane & 15, fs = lane >> 4;
  const int so = (fs ^ (fr & 3)) * 8;          // read-side swizzle

  f32x4 accg[4][2], accu[4][2];
  #pragma unroll
  for (int fi = 0; fi < 4; ++fi)
    #pragma unroll
    for (int fj = 0; fj < 2; ++fj) {
      accg[fi][fj] = f32x4{0.f, 0.f, 0.f, 0.f};
      accu[fi][fj] = f32x4{0.f, 0.f, 0.f, 0.f};
    }

  auto stage = [&](int kt, int b) {
    const int ko = kt * 32;
    #pragma unroll
    for (int i = 0; i < 2; ++i)
      gload16(srcA[i] + ko, &ldsA[b][(wid * 2 + i) * 512]);
    gload16(srcG + ko, &ldsG[b][wid * 512]);
    gload16(srcU + ko, &ldsU[b][wid * 512]);
  };

  auto compute = [&](int b) {
    const short* Ab = ldsA[b]; const short* Gb = ldsG[b]; const short* Ub = ldsU[b];
    bf16x8 af[4], bg[2], bu[2];
    #pragma unroll
    for (int fi = 0; fi < 4; ++fi)
      af[fi] = *(const bf16x8*)&Ab[(wm * 64 + fi * 16 + fr) * 32 + so];
    #pragma unroll
    for (int fj = 0; fj < 2; ++fj) {
      bg[fj] = *(const bf16x8*)&Gb[(wn * 32 + fj * 16 + fr) * 32 + so];
      bu[fj] = *(const bf16x8*)&Ub[(wn * 32 + fj * 16 + fr) * 32 + so];
    }
    #pragma unroll
    for (int fi = 0; fi < 4; ++fi)
      #pragma unroll
      for (int fj = 0; fj < 2; ++fj) {
        accg[fi][fj] = __builtin_amdgcn_mfma_f32_16x16x32_bf16(af[fi], bg[fj], accg[fi][fj], 0, 0, 0);
        accu[fi][fj] = __builtin_amdgcn_mfma_f32_16x16x32_bf16(af[fi], bu[fj], accu[fi][fj], 0, 0, 0);
      }
  };

  const int KT = D_MODEL / 32;  // 128
  stage(0, 0);
  for (int kt = 0; kt < KT; ++kt) {
    const int cur = kt & 1;
    __syncthreads();                       // drains stage(kt) vmcnt
    if (kt + 1 < KT) stage(kt + 1, cur ^ 1);
    compute(cur);
  }

  const int offs_e = offs[e];
  #pragma unroll
  for (int fi = 0; fi < 4; ++fi)
    #pragma unroll
    for (int fj = 0; fj < 2; ++fj)
      #pragma unroll
      for (int j = 0; j < 4; ++j) {
        const int r = m0 + wm * 64 + fi * 16 + fs * 4 + j;
        if (r < n_e) {
          const int c = h0 + wn * 32 + fj * 16 + fr;
          const float sc = pair_scr[e * NTOK + r];
          const float g  = accg[fi][fj][j];
          const float u  = accu[fi][fj][j];
          const float hv = (g / (1.f + expf(-g))) * u * sc;
          H[(size_t)(offs_e + r) * HIDP + c] = f2bf(hv);
        }
      }
}

// ================================================================ stage 2
// BM=128, BN=128, BK=32 double-buffered (32 KiB LDS). Grid 32*512, dt slowest.
__global__ __launch_bounds__(256, 4) void stage2b_kernel(
    const short* __restrict__ H, const short* __restrict__ wdb,
    const int* __restrict__ counts, const int* __restrict__ offs,
    const int* __restrict__ pair_tok, float* __restrict__ y)
{
  const int bid = blockIdx.x;
  const int dt  = bid >> 9;            // 0..31 (slowest)
  const int q   = bid & 511;
  const int xcd = q & 7;
  const int idx = q >> 3;
  const int e   = xcd * 2 + (idx & 1);
  const int mt  = idx >> 1;

  const int n_e = counts[e];
  const int m0  = mt * 128;
  if (m0 >= n_e) return;
  const int d0  = dt * 128;

  __shared__ short ldsA[2][128 * 32];
  __shared__ short ldsB[2][128 * 32];

  const int tid  = threadIdx.x;
  const int lane = tid & 63;
  const int wid  = tid >> 6;
  const int offs_e = offs[e];

  const short* srcA[2]; const short* srcB[2];
  #pragma unroll
  for (int i = 0; i < 2; ++i) {
    const int c    = wid * 2 + i;
    const int row  = 16 * c + (lane >> 2);
    const int slot = (lane & 3) ^ (row & 3);
    int r = m0 + row; if (r >= n_e) r = n_e - 1;
    srcA[i] = H + (size_t)(offs_e + r) * HIDP + slot * 8;
    srcB[i] = wdb + ((size_t)e * D_MODEL + d0 + row) * HIDP + slot * 8;
  }

  const int wm = wid >> 1, wn = wid & 1;
  const int fr = lane & 15, fs = lane >> 4;
  const int so = (fs ^ (fr & 3)) * 8;

  f32x4 acc[4][4];
  #pragma unroll
  for (int fi = 0; fi < 4; ++fi)
    #pragma unroll
    for (int fj = 0; fj < 4; ++fj) acc[fi][fj] = f32x4{0.f, 0.f, 0.f, 0.f};

  auto stage = [&](int kt, int b) {
    const int ko = kt * 32;
    #pragma unroll
    for (int i = 0; i < 2; ++i) {
      gload16(srcA[i] + ko, &ldsA[b][(wid * 2 + i) * 512]);
      gload16(srcB[i] + ko, &ldsB[b][(wid * 2 + i) * 512]);
    }
  };

  auto compute = [&](int b) {
    const short* Ab = ldsA[b]; const short* Bb = ldsB[b];
    bf16x8 af[4], bb[4];
    #pragma unroll
    for (int fi = 0; fi < 4; ++fi)
      af[fi] = *(const bf16x8*)&Ab[(wm * 64 + fi * 16 + fr) * 32 + so];
    #pragma unroll
    for (int fj = 0; fj < 4; ++fj)
      bb[fj] = *(const bf16x8*)&Bb[(wn * 64 + fj * 16 + fr) * 32 + so];
    #pragma unroll
    for (int fi = 0; fi < 4; ++fi)
      #pragma unroll
      for (int fj = 0; fj < 4; ++fj)
        acc[fi][fj] = __builtin_amdgcn_mfma_f32_16x16x32_bf16(af[fi], bb[fj], acc[fi][fj], 0, 0, 0);
  };

  const int KT = HIDP / 32;  // 22
  stage(0, 0);
  for (int kt = 0; kt < KT; ++kt) {
    const int cur = kt & 1;
    __syncthreads();
    if (kt + 1 < KT) stage(kt + 1, cur ^ 1);
    compute(cur);
  }

  #pragma unroll
  for (int fi = 0; fi < 4; ++fi)
    #pragma unroll
    for (int j = 0; j < 4; ++j) {
      const int r = m0 + wm * 64 + fi * 16 + fs * 4 + j;
      if (r < n_e) {
        const int tok = pair_tok[e * NTOK + r];
        float* yr = y + (size_t)tok * D_MODEL + d0 + wn * 64 + fr;
        #pragma unroll
        for (int fj = 0; fj < 4; ++fj)
          atomicAdd(yr + fj * 16, acc[fi][fj][j]);
      }
    }
}

// ---------------------------------------------------------------- launch
extern "C" void kernel_launch(void* const* d_in, const int* in_sizes, int n_in,
                              void* d_out, int out_size, void* d_ws, size_t ws_size,
                              hipStream_t stream) {
  const float* x     = (const float*)d_in[0];
  const float* wgate = (const float*)d_in[1];
  const float* w_g   = (const float*)d_in[2];
  const float* w_u   = (const float*)d_in[3];
  const float* w_d   = (const float*)d_in[4];

  float* y        = (float*)d_out;
  float* loss_out = y + (size_t)NTOK * D_MODEL;

  char* ws = (char*)d_ws;
  int*   counts     = (int*)ws;
  int*   offs       = counts + 16;
  float* importance = (float*)(counts + 32);
  int*   pair_tok   = (int*)(ws + 256);
  float* pair_scr   = (float*)(ws + 256 + (size_t)NEXP * NTOK * 4);
  short* H          = (short*)(ws + 256 + (size_t)2 * NEXP * NTOK * 4);

  const size_t H_BYTES  = (size_t)NTOK * NSEL * HIDP * 2;
  short* xbuf = (short*)((char*)H + H_BYTES);
  short* wgb  = xbuf + (size_t)NTOK * D_MODEL;
  short* wub  = wgb + (size_t)NEXP * HIDP * D_MODEL;
  short* wdb  = wub + (size_t)NEXP * HIDP * D_MODEL;

  hipLaunchKernelGGL(zero_meta_kernel, dim3(1), dim3(64), 0, stream, counts, importance);
  hipLaunchKernelGGL(zero_y_kernel, dim3(16384), dim3(256), 0, stream, y);
  hipLaunchKernelGGL(gate_kernel, dim3(NTOK), dim3(256), 0, stream,
                     x, wgate, counts, importance, pair_tok, pair_scr);
  hipLaunchKernelGGL(scan_loss_kernel, dim3(1), dim3(64), 0, stream,
                     counts, importance, offs, loss_out);

  hipLaunchKernelGGL(conv_x_kernel,   dim3(2048), dim3(256), 0, stream, x, xbuf);
  hipLaunchKernelGGL(conv_wgu_kernel, dim3(4096), dim3(256), 0, stream, w_g, w_u, wgb, wub);
  hipLaunchKernelGGL(conv_wd_kernel,  dim3(4096), dim3(256), 0, stream, w_d, wdb);
  hipLaunchKernelGGL(stage1b_kernel, dim3(11 * 512), dim3(256), 0, stream,
                     xbuf, wgb, wub, counts, offs, pair_tok, pair_scr, H);
  hipLaunchKernelGGL(stage2b_kernel, dim3(32 * 512), dim3(256), 0, stream,
                     H, wdb, counts, offs, pair_tok, y);
}

// Round 4
// 968.118 us; speedup vs baseline: 1.4609x; 1.0613x over previous
//
#include <hip/hip_runtime.h>
#include <hip/hip_bf16.h>

#define D_MODEL 4096
#define NEXP    16
#define HID     688
#define HIDP    704
#define NSEL    4
#define NTOK    4096

typedef __attribute__((ext_vector_type(4))) float  f32x4;
typedef __attribute__((ext_vector_type(8))) short  bf16x8;

__device__ __forceinline__ short f2bf(float f) {
  __hip_bfloat16 h = __float2bfloat16(f);
  return __builtin_bit_cast(short, h);
}

__device__ __forceinline__ void gload16(const void* g, void* l) {
  __builtin_amdgcn_global_load_lds(
      (const __attribute__((address_space(1))) unsigned int*)g,
      (__attribute__((address_space(3))) unsigned int*)l, 16, 0, 0);
}

// ---------------------------------------------------------------- zero init
__global__ void zero_meta_kernel(int* counts, float* importance) {
  const int tid = threadIdx.x;
  if (tid < NEXP) counts[tid] = 0;
  else if (tid < 2 * NEXP) importance[tid - NEXP] = 0.f;
}

__global__ void zero_y_kernel(float* __restrict__ y) {
  const size_t i = (size_t)blockIdx.x * 256 + threadIdx.x;
  *(f32x4*)(y + i * 4) = f32x4{0.f, 0.f, 0.f, 0.f};
}

// ---------------------------------------------------------------- gate
__global__ __launch_bounds__(256) void gate_kernel(
    const float* __restrict__ x, const float* __restrict__ wg,
    int* __restrict__ counts, float* __restrict__ importance,
    int* __restrict__ pair_tok, float* __restrict__ pair_scr,
    int* __restrict__ pair_rank)
{
  const int t   = blockIdx.x;
  const int tid = threadIdx.x;
  const float* xr = x + (size_t)t * D_MODEL;

  double acc[NEXP];
  #pragma unroll
  for (int e = 0; e < NEXP; ++e) acc[e] = 0.0;

  for (int i = tid; i < D_MODEL; i += 256) {
    const float xv = xr[i];
    const f32x4* w = (const f32x4*)(wg + (size_t)i * NEXP);
    #pragma unroll
    for (int q = 0; q < 4; ++q) {
      const f32x4 wv = w[q];
      #pragma unroll
      for (int j = 0; j < 4; ++j) acc[q * 4 + j] += (double)xv * (double)wv[j];
    }
  }

  #pragma unroll
  for (int e = 0; e < NEXP; ++e) {
    double v = acc[e];
    #pragma unroll
    for (int off = 32; off > 0; off >>= 1) v += __shfl_xor(v, off, 64);
    acc[e] = v;
  }

  __shared__ double red[4][NEXP];
  const int lane = tid & 63, wid = tid >> 6;
  if (lane == 0) {
    #pragma unroll
    for (int e = 0; e < NEXP; ++e) red[wid][e] = acc[e];
  }
  __syncthreads();

  if (tid == 0) {
    float lg[NEXP];
    #pragma unroll
    for (int e = 0; e < NEXP; ++e)
      lg[e] = (float)(red[0][e] + red[1][e] + red[2][e] + red[3][e]);

    int   idx[NSEL];
    float val[NSEL];
    unsigned used = 0;
    for (int k = 0; k < NSEL; ++k) {
      float best = -3.4e38f; int bi = 0;
      for (int e = 0; e < NEXP; ++e)
        if (!((used >> e) & 1u) && lg[e] > best) { best = lg[e]; bi = e; }
      idx[k] = bi; val[k] = best; used |= 1u << bi;
    }
    const float m = val[0];
    float ex[NSEL], s = 0.f;
    for (int k = 0; k < NSEL; ++k) { ex[k] = expf(val[k] - m); s += ex[k]; }
    for (int k = 0; k < NSEL; ++k) {
      const float sc = ex[k] / s;
      const int e = idx[k];
      const int pos = atomicAdd(&counts[e], 1);
      pair_tok[e * NTOK + pos]  = t;
      pair_scr[e * NTOK + pos]  = sc;
      pair_rank[e * NTOK + pos] = k;
      atomicAdd(&importance[e], sc);
    }
  }
}

// ---------------------------------------------------------------- scan + balance loss
__global__ void scan_loss_kernel(const int* __restrict__ counts,
                                 const float* __restrict__ importance,
                                 int* __restrict__ offs, float* __restrict__ loss_out)
{
  if (threadIdx.x != 0 || blockIdx.x != 0) return;
  int   c[NEXP]; float im[NEXP];
  for (int e = 0; e < NEXP; ++e) { c[e] = counts[e]; im[e] = importance[e]; }
  int o = 0;
  for (int e = 0; e < NEXP; ++e) { offs[e] = o; o += c[e]; }
  float mi = 0.f, ml = 0.f;
  for (int e = 0; e < NEXP; ++e) { mi += im[e]; ml += (float)c[e]; }
  mi /= NEXP; ml /= NEXP;
  float vi = 0.f, vl = 0.f;
  for (int e = 0; e < NEXP; ++e) {
    vi += (im[e] - mi) * (im[e] - mi);
    vl += ((float)c[e] - ml) * ((float)c[e] - ml);
  }
  vi /= (NEXP - 1); vl /= (NEXP - 1);
  const float loss = 0.01f * (vi / (mi * mi + 1e-10f) + vl / (ml * ml + 1e-10f));
  *loss_out = loss;
}

// ---------------------------------------------------------------- fp32 -> bf16 conversion passes
__global__ __launch_bounds__(256) void conv_x_kernel(const float* __restrict__ src,
                                                     short* __restrict__ dst) {
  const size_t stride = (size_t)gridDim.x * 256;
  const size_t n8 = (size_t)NTOK * D_MODEL / 8;
  for (size_t i = (size_t)blockIdx.x * 256 + threadIdx.x; i < n8; i += stride) {
    const f32x4 a = *(const f32x4*)(src + i * 8);
    const f32x4 b = *(const f32x4*)(src + i * 8 + 4);
    bf16x8 o;
    #pragma unroll
    for (int j = 0; j < 4; ++j) { o[j] = f2bf(a[j]); o[4 + j] = f2bf(b[j]); }
    *(bf16x8*)(dst + i * 8) = o;
  }
}

__global__ __launch_bounds__(256) void conv_wgu_kernel(
    const float* __restrict__ g, const float* __restrict__ u,
    short* __restrict__ gb, short* __restrict__ ub) {
  const size_t stride = (size_t)gridDim.x * 256;
  const size_t n8 = (size_t)NEXP * HIDP * (D_MODEL / 8);
  for (size_t i = (size_t)blockIdx.x * 256 + threadIdx.x; i < n8; i += stride) {
    const int c8  = (int)(i & 511);
    const int row = (int)((i >> 9) % HIDP);
    const int e   = (int)(i / (512 * HIDP));
    bf16x8 og, ou;
    if (row < HID) {
      const size_t so = ((size_t)e * HID + row) * D_MODEL + (size_t)c8 * 8;
      const f32x4 ga = *(const f32x4*)(g + so);
      const f32x4 gbv = *(const f32x4*)(g + so + 4);
      const f32x4 ua = *(const f32x4*)(u + so);
      const f32x4 ubv = *(const f32x4*)(u + so + 4);
      #pragma unroll
      for (int j = 0; j < 4; ++j) {
        og[j] = f2bf(ga[j]); og[4 + j] = f2bf(gbv[j]);
        ou[j] = f2bf(ua[j]); ou[4 + j] = f2bf(ubv[j]);
      }
    } else {
      #pragma unroll
      for (int j = 0; j < 8; ++j) { og[j] = 0; ou[j] = 0; }
    }
    *(bf16x8*)(gb + i * 8) = og;
    *(bf16x8*)(ub + i * 8) = ou;
  }
}

__global__ __launch_bounds__(256) void conv_wd_kernel(const float* __restrict__ w,
                                                      short* __restrict__ wb) {
  const size_t stride = (size_t)gridDim.x * 256;
  const size_t n8 = (size_t)NEXP * D_MODEL * (HIDP / 8);
  for (size_t i = (size_t)blockIdx.x * 256 + threadIdx.x; i < n8; i += stride) {
    const int c8  = (int)(i % 88);
    const int row = (int)((i / 88) & (D_MODEL - 1));
    const int e   = (int)(i / (88 * D_MODEL));
    bf16x8 o;
    if (c8 < 86) {
      const size_t so = ((size_t)e * D_MODEL + row) * HID + (size_t)c8 * 8;
      const f32x4 a = *(const f32x4*)(w + so);
      const f32x4 b = *(const f32x4*)(w + so + 4);
      #pragma unroll
      for (int j = 0; j < 4; ++j) { o[j] = f2bf(a[j]); o[4 + j] = f2bf(b[j]); }
    } else {
      #pragma unroll
      for (int j = 0; j < 8; ++j) o[j] = 0;
    }
    *(bf16x8*)(wb + i * 8) = o;
  }
}

// ================================================================ stage 1
// BM=128, BN=64(g)+64(u), BK=32 dbuf. Swizzle: 64B rows, 4 slots of 16B,
// physical slot = logical ^ ((row>>1)&3)  -> <=2-way bank aliasing (free).
__global__ __launch_bounds__(256, 4) void stage1b_kernel(
    const short* __restrict__ xb, const short* __restrict__ wgb,
    const short* __restrict__ wub, const int* __restrict__ counts,
    const int* __restrict__ offs, const int* __restrict__ pair_tok,
    const float* __restrict__ pair_scr, short* __restrict__ H)
{
  const int bid = blockIdx.x;
  const int ht  = bid >> 9;            // 0..10 (slowest)
  const int q   = bid & 511;
  const int xcd = q & 7;
  const int idx = q >> 3;
  const int e   = xcd * 2 + (idx & 1);
  const int mt  = idx >> 1;

  const int n_e = counts[e];
  const int m0  = mt * 128;
  if (m0 >= n_e) return;
  const int h0  = ht * 64;

  __shared__ short ldsA[2][128 * 32];
  __shared__ short ldsG[2][64 * 32];
  __shared__ short ldsU[2][64 * 32];

  const int tid  = threadIdx.x;
  const int lane = tid & 63;
  const int wid  = tid >> 6;

  const short* srcA[2]; const short* srcG; const short* srcU;
  #pragma unroll
  for (int i = 0; i < 2; ++i) {
    const int c    = wid * 2 + i;
    const int row  = 16 * c + (lane >> 2);
    const int slot = (lane & 3) ^ ((row >> 1) & 3);
    int r = m0 + row; if (r >= n_e) r = n_e - 1;
    const int tok = pair_tok[e * NTOK + r];
    srcA[i] = xb + (size_t)tok * D_MODEL + slot * 8;
  }
  {
    const int c    = wid;
    const int row  = 16 * c + (lane >> 2);
    const int slot = (lane & 3) ^ ((row >> 1) & 3);
    const size_t rb = ((size_t)e * HIDP + h0 + row) * D_MODEL + slot * 8;
    srcG = wgb + rb;
    srcU = wub + rb;
  }

  const int wm = wid >> 1, wn = wid & 1;
  const int fr = lane & 15, fs = lane >> 4;
  const int so = (fs ^ ((fr >> 1) & 3)) * 8;   // read-side swizzle (row q = (fr>>1)&3)

  f32x4 accg[4][2], accu[4][2];
  #pragma unroll
  for (int fi = 0; fi < 4; ++fi)
    #pragma unroll
    for (int fj = 0; fj < 2; ++fj) {
      accg[fi][fj] = f32x4{0.f, 0.f, 0.f, 0.f};
      accu[fi][fj] = f32x4{0.f, 0.f, 0.f, 0.f};
    }

  auto stage = [&](int kt, int b) {
    const int ko = kt * 32;
    #pragma unroll
    for (int i = 0; i < 2; ++i)
      gload16(srcA[i] + ko, &ldsA[b][(wid * 2 + i) * 512]);
    gload16(srcG + ko, &ldsG[b][wid * 512]);
    gload16(srcU + ko, &ldsU[b][wid * 512]);
  };

  auto compute = [&](int b) {
    const short* Ab = ldsA[b]; const short* Gb = ldsG[b]; const short* Ub = ldsU[b];
    bf16x8 af[4], bg[2], bu[2];
    #pragma unroll
    for (int fi = 0; fi < 4; ++fi)
      af[fi] = *(const bf16x8*)&Ab[(wm * 64 + fi * 16 + fr) * 32 + so];
    #pragma unroll
    for (int fj = 0; fj < 2; ++fj) {
      bg[fj] = *(const bf16x8*)&Gb[(wn * 32 + fj * 16 + fr) * 32 + so];
      bu[fj] = *(const bf16x8*)&Ub[(wn * 32 + fj * 16 + fr) * 32 + so];
    }
    #pragma unroll
    for (int fi = 0; fi < 4; ++fi)
      #pragma unroll
      for (int fj = 0; fj < 2; ++fj) {
        accg[fi][fj] = __builtin_amdgcn_mfma_f32_16x16x32_bf16(af[fi], bg[fj], accg[fi][fj], 0, 0, 0);
        accu[fi][fj] = __builtin_amdgcn_mfma_f32_16x16x32_bf16(af[fi], bu[fj], accu[fi][fj], 0, 0, 0);
      }
  };

  const int KT = D_MODEL / 32;  // 128
  stage(0, 0);
  for (int kt = 0; kt < KT; ++kt) {
    const int cur = kt & 1;
    __syncthreads();
    if (kt + 1 < KT) stage(kt + 1, cur ^ 1);
    compute(cur);
  }

  const int offs_e = offs[e];
  #pragma unroll
  for (int fi = 0; fi < 4; ++fi)
    #pragma unroll
    for (int fj = 0; fj < 2; ++fj)
      #pragma unroll
      for (int j = 0; j < 4; ++j) {
        const int r = m0 + wm * 64 + fi * 16 + fs * 4 + j;
        if (r < n_e) {
          const int c = h0 + wn * 32 + fj * 16 + fr;
          const float sc = pair_scr[e * NTOK + r];
          const float g  = accg[fi][fj][j];
          const float u  = accu[fi][fj][j];
          const float hv = (g / (1.f + expf(-g))) * u * sc;
          H[(size_t)(offs_e + r) * HIDP + c] = f2bf(hv);
        }
      }
}

// ================================================================ stage 2 (store path)
// BM=128, BN=128, BK=32 dbuf; plain stores into rank plane Yk[k][t][d].
__global__ __launch_bounds__(256, 4) void stage2s_kernel(
    const short* __restrict__ H, const short* __restrict__ wdb,
    const int* __restrict__ counts, const int* __restrict__ offs,
    const int* __restrict__ pair_tok, const int* __restrict__ pair_rank,
    float* __restrict__ Yk)
{
  const int bid = blockIdx.x;
  const int dt  = bid >> 9;
  const int q   = bid & 511;
  const int xcd = q & 7;
  const int idx = q >> 3;
  const int e   = xcd * 2 + (idx & 1);
  const int mt  = idx >> 1;

  const int n_e = counts[e];
  const int m0  = mt * 128;
  if (m0 >= n_e) return;
  const int d0  = dt * 128;

  __shared__ short ldsA[2][128 * 32];
  __shared__ short ldsB[2][128 * 32];

  const int tid  = threadIdx.x;
  const int lane = tid & 63;
  const int wid  = tid >> 6;
  const int offs_e = offs[e];

  const short* srcA[2]; const short* srcB[2];
  #pragma unroll
  for (int i = 0; i < 2; ++i) {
    const int c    = wid * 2 + i;
    const int row  = 16 * c + (lane >> 2);
    const int slot = (lane & 3) ^ ((row >> 1) & 3);
    int r = m0 + row; if (r >= n_e) r = n_e - 1;
    srcA[i] = H + (size_t)(offs_e + r) * HIDP + slot * 8;
    srcB[i] = wdb + ((size_t)e * D_MODEL + d0 + row) * HIDP + slot * 8;
  }

  const int wm = wid >> 1, wn = wid & 1;
  const int fr = lane & 15, fs = lane >> 4;
  const int so = (fs ^ ((fr >> 1) & 3)) * 8;

  f32x4 acc[4][4];
  #pragma unroll
  for (int fi = 0; fi < 4; ++fi)
    #pragma unroll
    for (int fj = 0; fj < 4; ++fj) acc[fi][fj] = f32x4{0.f, 0.f, 0.f, 0.f};

  auto stage = [&](int kt, int b) {
    const int ko = kt * 32;
    #pragma unroll
    for (int i = 0; i < 2; ++i) {
      gload16(srcA[i] + ko, &ldsA[b][(wid * 2 + i) * 512]);
      gload16(srcB[i] + ko, &ldsB[b][(wid * 2 + i) * 512]);
    }
  };

  auto compute = [&](int b) {
    const short* Ab = ldsA[b]; const short* Bb = ldsB[b];
    bf16x8 af[4], bb[4];
    #pragma unroll
    for (int fi = 0; fi < 4; ++fi)
      af[fi] = *(const bf16x8*)&Ab[(wm * 64 + fi * 16 + fr) * 32 + so];
    #pragma unroll
    for (int fj = 0; fj < 4; ++fj)
      bb[fj] = *(const bf16x8*)&Bb[(wn * 64 + fj * 16 + fr) * 32 + so];
    #pragma unroll
    for (int fi = 0; fi < 4; ++fi)
      #pragma unroll
      for (int fj = 0; fj < 4; ++fj)
        acc[fi][fj] = __builtin_amdgcn_mfma_f32_16x16x32_bf16(af[fi], bb[fj], acc[fi][fj], 0, 0, 0);
  };

  const int KT = HIDP / 32;  // 22
  stage(0, 0);
  for (int kt = 0; kt < KT; ++kt) {
    const int cur = kt & 1;
    __syncthreads();
    if (kt + 1 < KT) stage(kt + 1, cur ^ 1);
    compute(cur);
  }

  #pragma unroll
  for (int fi = 0; fi < 4; ++fi)
    #pragma unroll
    for (int j = 0; j < 4; ++j) {
      const int r = m0 + wm * 64 + fi * 16 + fs * 4 + j;
      if (r < n_e) {
        const int tok = pair_tok[e * NTOK + r];
        const int rk  = pair_rank[e * NTOK + r];
        float* yr = Yk + ((size_t)rk * NTOK + tok) * D_MODEL + d0 + wn * 64 + fr;
        #pragma unroll
        for (int fj = 0; fj < 4; ++fj)
          yr[fj * 16] = acc[fi][fj][j];
      }
    }
}

__global__ __launch_bounds__(256) void reduce_y_kernel(const float* __restrict__ Yk,
                                                       float* __restrict__ y) {
  const size_t i = ((size_t)blockIdx.x * 256 + threadIdx.x) * 4;
  const size_t P = (size_t)NTOK * D_MODEL;
  f32x4 s = *(const f32x4*)(Yk + i);
  s += *(const f32x4*)(Yk + P + i);
  s += *(const f32x4*)(Yk + 2 * P + i);
  s += *(const f32x4*)(Yk + 3 * P + i);
  *(f32x4*)(y + i) = s;
}

// ================================================================ stage 2 (atomic fallback)
__global__ __launch_bounds__(256, 4) void stage2a_kernel(
    const short* __restrict__ H, const short* __restrict__ wdb,
    const int* __restrict__ counts, const int* __restrict__ offs,
    const int* __restrict__ pair_tok, float* __restrict__ y)
{
  const int bid = blockIdx.x;
  const int dt  = bid >> 9;
  const int q   = bid & 511;
  const int xcd = q & 7;
  const int idx = q >> 3;
  const int e   = xcd * 2 + (idx & 1);
  const int mt  = idx >> 1;

  const int n_e = counts[e];
  const int m0  = mt * 128;
  if (m0 >= n_e) return;
  const int d0  = dt * 128;

  __shared__ short ldsA[2][128 * 32];
  __shared__ short ldsB[2][128 * 32];

  const int tid  = threadIdx.x;
  const int lane = tid & 63;
  const int wid  = tid >> 6;
  const int offs_e = offs[e];

  const short* srcA[2]; const short* srcB[2];
  #pragma unroll
  for (int i = 0; i < 2; ++i) {
    const int c    = wid * 2 + i;
    const int row  = 16 * c + (lane >> 2);
    const int slot = (lane & 3) ^ ((row >> 1) & 3);
    int r = m0 + row; if (r >= n_e) r = n_e - 1;
    srcA[i] = H + (size_t)(offs_e + r) * HIDP + slot * 8;
    srcB[i] = wdb + ((size_t)e * D_MODEL + d0 + row) * HIDP + slot * 8;
  }

  const int wm = wid >> 1, wn = wid & 1;
  const int fr = lane & 15, fs = lane >> 4;
  const int so = (fs ^ ((fr >> 1) & 3)) * 8;

  f32x4 acc[4][4];
  #pragma unroll
  for (int fi = 0; fi < 4; ++fi)
    #pragma unroll
    for (int fj = 0; fj < 4; ++fj) acc[fi][fj] = f32x4{0.f, 0.f, 0.f, 0.f};

  auto stage = [&](int kt, int b) {
    const int ko = kt * 32;
    #pragma unroll
    for (int i = 0; i < 2; ++i) {
      gload16(srcA[i] + ko, &ldsA[b][(wid * 2 + i) * 512]);
      gload16(srcB[i] + ko, &ldsB[b][(wid * 2 + i) * 512]);
    }
  };

  auto compute = [&](int b) {
    const short* Ab = ldsA[b]; const short* Bb = ldsB[b];
    bf16x8 af[4], bb[4];
    #pragma unroll
    for (int fi = 0; fi < 4; ++fi)
      af[fi] = *(const bf16x8*)&Ab[(wm * 64 + fi * 16 + fr) * 32 + so];
    #pragma unroll
    for (int fj = 0; fj < 4; ++fj)
      bb[fj] = *(const bf16x8*)&Bb[(wn * 64 + fj * 16 + fr) * 32 + so];
    #pragma unroll
    for (int fi = 0; fi < 4; ++fi)
      #pragma unroll
      for (int fj = 0; fj < 4; ++fj)
        acc[fi][fj] = __builtin_amdgcn_mfma_f32_16x16x32_bf16(af[fi], bb[fj], acc[fi][fj], 0, 0, 0);
  };

  const int KT = HIDP / 32;
  stage(0, 0);
  for (int kt = 0; kt < KT; ++kt) {
    const int cur = kt & 1;
    __syncthreads();
    if (kt + 1 < KT) stage(kt + 1, cur ^ 1);
    compute(cur);
  }

  #pragma unroll
  for (int fi = 0; fi < 4; ++fi)
    #pragma unroll
    for (int j = 0; j < 4; ++j) {
      const int r = m0 + wm * 64 + fi * 16 + fs * 4 + j;
      if (r < n_e) {
        const int tok = pair_tok[e * NTOK + r];
        float* yr = y + (size_t)tok * D_MODEL + d0 + wn * 64 + fr;
        #pragma unroll
        for (int fj = 0; fj < 4; ++fj)
          atomicAdd(yr + fj * 16, acc[fi][fj][j]);
      }
    }
}

// ---------------------------------------------------------------- launch
extern "C" void kernel_launch(void* const* d_in, const int* in_sizes, int n_in,
                              void* d_out, int out_size, void* d_ws, size_t ws_size,
                              hipStream_t stream) {
  const float* x     = (const float*)d_in[0];
  const float* wgate = (const float*)d_in[1];
  const float* w_g   = (const float*)d_in[2];
  const float* w_u   = (const float*)d_in[3];
  const float* w_d   = (const float*)d_in[4];

  float* y        = (float*)d_out;
  float* loss_out = y + (size_t)NTOK * D_MODEL;

  char* ws = (char*)d_ws;
  int*   counts     = (int*)ws;
  int*   offs       = counts + 16;
  float* importance = (float*)(counts + 32);
  int*   pair_tok   = (int*)(ws + 256);
  float* pair_scr   = (float*)(ws + 256 + (size_t)NEXP * NTOK * 4);
  int*   pair_rank  = (int*)(ws + 256 + (size_t)2 * NEXP * NTOK * 4);
  short* H          = (short*)(ws + 256 + (size_t)3 * NEXP * NTOK * 4);

  const size_t H_BYTES = (size_t)NTOK * NSEL * HIDP * 2;
  short* xbuf = (short*)((char*)H + H_BYTES);
  short* wgb  = xbuf + (size_t)NTOK * D_MODEL;
  short* wub  = wgb + (size_t)NEXP * HIDP * D_MODEL;
  short* wdb  = wub + (size_t)NEXP * HIDP * D_MODEL;
  float* Yk   = (float*)(wdb + (size_t)NEXP * HIDP * D_MODEL);

  const size_t NEED_STORE = ((char*)(Yk + (size_t)NSEL * NTOK * D_MODEL)) - ws;
  const bool store_path = ws_size >= NEED_STORE;

  hipLaunchKernelGGL(zero_meta_kernel, dim3(1), dim3(64), 0, stream, counts, importance);
  hipLaunchKernelGGL(gate_kernel, dim3(NTOK), dim3(256), 0, stream,
                     x, wgate, counts, importance, pair_tok, pair_scr, pair_rank);
  hipLaunchKernelGGL(scan_loss_kernel, dim3(1), dim3(64), 0, stream,
                     counts, importance, offs, loss_out);

  hipLaunchKernelGGL(conv_x_kernel,   dim3(2048), dim3(256), 0, stream, x, xbuf);
  hipLaunchKernelGGL(conv_wgu_kernel, dim3(4096), dim3(256), 0, stream, w_g, w_u, wgb, wub);
  hipLaunchKernelGGL(conv_wd_kernel,  dim3(4096), dim3(256), 0, stream, w_d, wdb);
  hipLaunchKernelGGL(stage1b_kernel, dim3(11 * 512), dim3(256), 0, stream,
                     xbuf, wgb, wub, counts, offs, pair_tok, pair_scr, H);

  if (store_path) {
    hipLaunchKernelGGL(stage2s_kernel, dim3(32 * 512), dim3(256), 0, stream,
                       H, wdb, counts, offs, pair_tok, pair_rank, Yk);
    hipLaunchKernelGGL(reduce_y_kernel, dim3(NTOK * D_MODEL / 4 / 256), dim3(256), 0, stream,
                       Yk, y);
  } else {
    hipLaunchKernelGGL(zero_y_kernel, dim3(16384), dim3(256), 0, stream, y);
    hipLaunchKernelGGL(stage2a_kernel, dim3(32 * 512), dim3(256), 0, stream,
                       H, wdb, counts, offs, pair_tok, y);
  }
}

// Round 5
// 961.274 us; speedup vs baseline: 1.4713x; 1.0071x over previous
//
#include <hip/hip_runtime.h>
#include <hip/hip_bf16.h>

#define D_MODEL 4096
#define NEXP    16
#define HID     688
#define HIDP    704
#define NSEL    4
#define NTOK    4096

typedef __attribute__((ext_vector_type(4))) float  f32x4;
typedef __attribute__((ext_vector_type(8))) short  bf16x8;

#define VMCNT(n) asm volatile("s_waitcnt vmcnt(" #n ")" ::: "memory")

__device__ __forceinline__ short f2bf(float f) {
  __hip_bfloat16 h = __float2bfloat16(f);
  return __builtin_bit_cast(short, h);
}

__device__ __forceinline__ void gload16(const void* g, void* l) {
  __builtin_amdgcn_global_load_lds(
      (const __attribute__((address_space(1))) unsigned int*)g,
      (__attribute__((address_space(3))) unsigned int*)l, 16, 0, 0);
}

// ---------------------------------------------------------------- zero init
__global__ void zero_meta_kernel(int* counts, float* importance) {
  const int tid = threadIdx.x;
  if (tid < NEXP) counts[tid] = 0;
  else if (tid < 2 * NEXP) importance[tid - NEXP] = 0.f;
}

__global__ void zero_y_kernel(float* __restrict__ y) {
  const size_t i = (size_t)blockIdx.x * 256 + threadIdx.x;
  *(f32x4*)(y + i * 4) = f32x4{0.f, 0.f, 0.f, 0.f};
}

// ---------------------------------------------------------------- gate (+ fused x->bf16 conversion)
__global__ __launch_bounds__(256) void gate_kernel(
    const float* __restrict__ x, const float* __restrict__ wg,
    int* __restrict__ counts, float* __restrict__ importance,
    int* __restrict__ pair_tok, float* __restrict__ pair_scr,
    int* __restrict__ pair_rank, short* __restrict__ xb)
{
  const int t   = blockIdx.x;
  const int tid = threadIdx.x;
  const float* xr = x + (size_t)t * D_MODEL;

  // fused conversion of this token's row to bf16
  {
    short* xbr = xb + (size_t)t * D_MODEL;
    for (int i8 = tid; i8 < D_MODEL / 8; i8 += 256) {
      const f32x4 a = *(const f32x4*)(xr + i8 * 8);
      const f32x4 b = *(const f32x4*)(xr + i8 * 8 + 4);
      bf16x8 o;
      #pragma unroll
      for (int j = 0; j < 4; ++j) { o[j] = f2bf(a[j]); o[4 + j] = f2bf(b[j]); }
      *(bf16x8*)(xbr + i8 * 8) = o;
    }
  }

  double acc[NEXP];
  #pragma unroll
  for (int e = 0; e < NEXP; ++e) acc[e] = 0.0;

  for (int i = tid; i < D_MODEL; i += 256) {
    const float xv = xr[i];
    const f32x4* w = (const f32x4*)(wg + (size_t)i * NEXP);
    #pragma unroll
    for (int q = 0; q < 4; ++q) {
      const f32x4 wv = w[q];
      #pragma unroll
      for (int j = 0; j < 4; ++j) acc[q * 4 + j] += (double)xv * (double)wv[j];
    }
  }

  #pragma unroll
  for (int e = 0; e < NEXP; ++e) {
    double v = acc[e];
    #pragma unroll
    for (int off = 32; off > 0; off >>= 1) v += __shfl_xor(v, off, 64);
    acc[e] = v;
  }

  __shared__ double red[4][NEXP];
  const int lane = tid & 63, wid = tid >> 6;
  if (lane == 0) {
    #pragma unroll
    for (int e = 0; e < NEXP; ++e) red[wid][e] = acc[e];
  }
  __syncthreads();

  if (tid == 0) {
    float lg[NEXP];
    #pragma unroll
    for (int e = 0; e < NEXP; ++e)
      lg[e] = (float)(red[0][e] + red[1][e] + red[2][e] + red[3][e]);

    int   idx[NSEL];
    float val[NSEL];
    unsigned used = 0;
    for (int k = 0; k < NSEL; ++k) {
      float best = -3.4e38f; int bi = 0;
      for (int e = 0; e < NEXP; ++e)
        if (!((used >> e) & 1u) && lg[e] > best) { best = lg[e]; bi = e; }
      idx[k] = bi; val[k] = best; used |= 1u << bi;
    }
    const float m = val[0];
    float ex[NSEL], s = 0.f;
    for (int k = 0; k < NSEL; ++k) { ex[k] = expf(val[k] - m); s += ex[k]; }
    for (int k = 0; k < NSEL; ++k) {
      const float sc = ex[k] / s;
      const int e = idx[k];
      const int pos = atomicAdd(&counts[e], 1);
      pair_tok[e * NTOK + pos]  = t;
      pair_scr[e * NTOK + pos]  = sc;
      pair_rank[e * NTOK + pos] = k;
      atomicAdd(&importance[e], sc);
    }
  }
}

// ---------------------------------------------------------------- scan + balance loss
__global__ void scan_loss_kernel(const int* __restrict__ counts,
                                 const float* __restrict__ importance,
                                 int* __restrict__ offs, float* __restrict__ loss_out)
{
  if (threadIdx.x != 0 || blockIdx.x != 0) return;
  int   c[NEXP]; float im[NEXP];
  for (int e = 0; e < NEXP; ++e) { c[e] = counts[e]; im[e] = importance[e]; }
  int o = 0;
  for (int e = 0; e < NEXP; ++e) { offs[e] = o; o += c[e]; }
  float mi = 0.f, ml = 0.f;
  for (int e = 0; e < NEXP; ++e) { mi += im[e]; ml += (float)c[e]; }
  mi /= NEXP; ml /= NEXP;
  float vi = 0.f, vl = 0.f;
  for (int e = 0; e < NEXP; ++e) {
    vi += (im[e] - mi) * (im[e] - mi);
    vl += ((float)c[e] - ml) * ((float)c[e] - ml);
  }
  vi /= (NEXP - 1); vl /= (NEXP - 1);
  const float loss = 0.01f * (vi / (mi * mi + 1e-10f) + vl / (ml * ml + 1e-10f));
  *loss_out = loss;
}

// ---------------------------------------------------------------- weight conversion passes
__global__ __launch_bounds__(256) void conv_wgu_kernel(
    const float* __restrict__ g, const float* __restrict__ u,
    short* __restrict__ gb, short* __restrict__ ub) {
  const size_t stride = (size_t)gridDim.x * 256;
  const size_t n8 = (size_t)NEXP * HIDP * (D_MODEL / 8);
  for (size_t i = (size_t)blockIdx.x * 256 + threadIdx.x; i < n8; i += stride) {
    const int c8  = (int)(i & 511);
    const int row = (int)((i >> 9) % HIDP);
    const int e   = (int)(i / (512 * HIDP));
    bf16x8 og, ou;
    if (row < HID) {
      const size_t so = ((size_t)e * HID + row) * D_MODEL + (size_t)c8 * 8;
      const f32x4 ga = *(const f32x4*)(g + so);
      const f32x4 gbv = *(const f32x4*)(g + so + 4);
      const f32x4 ua = *(const f32x4*)(u + so);
      const f32x4 ubv = *(const f32x4*)(u + so + 4);
      #pragma unroll
      for (int j = 0; j < 4; ++j) {
        og[j] = f2bf(ga[j]); og[4 + j] = f2bf(gbv[j]);
        ou[j] = f2bf(ua[j]); ou[4 + j] = f2bf(ubv[j]);
      }
    } else {
      #pragma unroll
      for (int j = 0; j < 8; ++j) { og[j] = 0; ou[j] = 0; }
    }
    *(bf16x8*)(gb + i * 8) = og;
    *(bf16x8*)(ub + i * 8) = ou;
  }
}

__global__ __launch_bounds__(256) void conv_wd_kernel(const float* __restrict__ w,
                                                      short* __restrict__ wb) {
  const size_t stride = (size_t)gridDim.x * 256;
  const size_t n8 = (size_t)NEXP * D_MODEL * (HIDP / 8);
  for (size_t i = (size_t)blockIdx.x * 256 + threadIdx.x; i < n8; i += stride) {
    const int c8  = (int)(i % 88);
    const int row = (int)((i / 88) & (D_MODEL - 1));
    const int e   = (int)(i / (88 * D_MODEL));
    bf16x8 o;
    if (c8 < 86) {
      const size_t so = ((size_t)e * D_MODEL + row) * HID + (size_t)c8 * 8;
      const f32x4 a = *(const f32x4*)(w + so);
      const f32x4 b = *(const f32x4*)(w + so + 4);
      #pragma unroll
      for (int j = 0; j < 4; ++j) { o[j] = f2bf(a[j]); o[4 + j] = f2bf(b[j]); }
    } else {
      #pragma unroll
      for (int j = 0; j < 8; ++j) o[j] = 0;
    }
    *(bf16x8*)(wb + i * 8) = o;
  }
}

// ================================================================ stage 1
// BM=128, BN=64(g)+64(u), BK=32, 3-buffer LDS, depth-2 prefetch with counted
// vmcnt (loads for kt+1/kt+2 stay in flight across barriers).
__global__ __launch_bounds__(256, 3) void stage1b_kernel(
    const short* __restrict__ xb, const short* __restrict__ wgb,
    const short* __restrict__ wub, const int* __restrict__ counts,
    const int* __restrict__ offs, const int* __restrict__ pair_tok,
    const float* __restrict__ pair_scr, short* __restrict__ H)
{
  const int bid = blockIdx.x;
  const int ht  = bid >> 9;            // 0..10 (slowest)
  const int q   = bid & 511;
  const int xcd = q & 7;
  const int idx = q >> 3;
  const int e   = xcd * 2 + (idx & 1);
  const int mt  = idx >> 1;

  const int n_e = counts[e];
  const int m0  = mt * 128;
  if (m0 >= n_e) return;
  const int h0  = ht * 64;

  __shared__ short ldsA[3][128 * 32];
  __shared__ short ldsG[3][64 * 32];
  __shared__ short ldsU[3][64 * 32];

  const int tid  = threadIdx.x;
  const int lane = tid & 63;
  const int wid  = tid >> 6;

  const short* srcA[2]; const short* srcG; const short* srcU;
  #pragma unroll
  for (int i = 0; i < 2; ++i) {
    const int c    = wid * 2 + i;
    const int row  = 16 * c + (lane >> 2);
    const int slot = (lane & 3) ^ ((row >> 1) & 3);
    int r = m0 + row; if (r >= n_e) r = n_e - 1;
    const int tok = pair_tok[e * NTOK + r];
    srcA[i] = xb + (size_t)tok * D_MODEL + slot * 8;
  }
  {
    const int c    = wid;
    const int row  = 16 * c + (lane >> 2);
    const int slot = (lane & 3) ^ ((row >> 1) & 3);
    const size_t rb = ((size_t)e * HIDP + h0 + row) * D_MODEL + slot * 8;
    srcG = wgb + rb;
    srcU = wub + rb;
  }

  const int wm = wid >> 1, wn = wid & 1;
  const int fr = lane & 15, fs = lane >> 4;
  const int so = (fs ^ ((fr >> 1) & 3)) * 8;

  f32x4 accg[4][2], accu[4][2];
  #pragma unroll
  for (int fi = 0; fi < 4; ++fi)
    #pragma unroll
    for (int fj = 0; fj < 2; ++fj) {
      accg[fi][fj] = f32x4{0.f, 0.f, 0.f, 0.f};
      accu[fi][fj] = f32x4{0.f, 0.f, 0.f, 0.f};
    }

  auto stage = [&](int kt, int b) {       // 4 vmem ops / thread
    const int ko = kt * 32;
    #pragma unroll
    for (int i = 0; i < 2; ++i)
      gload16(srcA[i] + ko, &ldsA[b][(wid * 2 + i) * 512]);
    gload16(srcG + ko, &ldsG[b][wid * 512]);
    gload16(srcU + ko, &ldsU[b][wid * 512]);
  };

  auto compute = [&](int b) {
    const short* Ab = ldsA[b]; const short* Gb = ldsG[b]; const short* Ub = ldsU[b];
    bf16x8 af[4], bg[2], bu[2];
    #pragma unroll
    for (int fi = 0; fi < 4; ++fi)
      af[fi] = *(const bf16x8*)&Ab[(wm * 64 + fi * 16 + fr) * 32 + so];
    #pragma unroll
    for (int fj = 0; fj < 2; ++fj) {
      bg[fj] = *(const bf16x8*)&Gb[(wn * 32 + fj * 16 + fr) * 32 + so];
      bu[fj] = *(const bf16x8*)&Ub[(wn * 32 + fj * 16 + fr) * 32 + so];
    }
    #pragma unroll
    for (int fi = 0; fi < 4; ++fi)
      #pragma unroll
      for (int fj = 0; fj < 2; ++fj) {
        accg[fi][fj] = __builtin_amdgcn_mfma_f32_16x16x32_bf16(af[fi], bg[fj], accg[fi][fj], 0, 0, 0);
        accu[fi][fj] = __builtin_amdgcn_mfma_f32_16x16x32_bf16(af[fi], bu[fj], accu[fi][fj], 0, 0, 0);
      }
  };

  const int KT = D_MODEL / 32;  // 128
  stage(0, 0);
  stage(1, 1);
  int cur = 0, tgt = 2;
  for (int kt = 0; kt < KT; ++kt) {
    __builtin_amdgcn_s_barrier();            // all waves done compute(kt-1): buf[tgt] free
    __builtin_amdgcn_sched_barrier(0);
    if (kt + 2 < KT) stage(kt + 2, tgt);
    if (kt + 2 < KT)      { VMCNT(8); }      // wait tile kt; kt+1,kt+2 in flight
    else if (kt + 1 < KT) { VMCNT(4); }
    else                  { VMCNT(0); }
    __builtin_amdgcn_s_barrier();            // buf[cur] loaded for everyone
    __builtin_amdgcn_sched_barrier(0);
    compute(cur);
    cur = (cur == 2) ? 0 : cur + 1;
    tgt = (tgt == 2) ? 0 : tgt + 1;
  }

  const int offs_e = offs[e];
  #pragma unroll
  for (int fi = 0; fi < 4; ++fi)
    #pragma unroll
    for (int fj = 0; fj < 2; ++fj)
      #pragma unroll
      for (int j = 0; j < 4; ++j) {
        const int r = m0 + wm * 64 + fi * 16 + fs * 4 + j;
        if (r < n_e) {
          const int c = h0 + wn * 32 + fj * 16 + fr;
          const float sc = pair_scr[e * NTOK + r];
          const float g  = accg[fi][fj][j];
          const float u  = accu[fi][fj][j];
          const float hv = (g / (1.f + expf(-g))) * u * sc;
          H[(size_t)(offs_e + r) * HIDP + c] = f2bf(hv);
        }
      }
}

// ================================================================ stage 2 (store path)
// BM=128, BN=128, BK=32, 3-buffer depth-2 counted-vmcnt; stores into Yk[k][t][d].
__global__ __launch_bounds__(256, 3) void stage2s_kernel(
    const short* __restrict__ H, const short* __restrict__ wdb,
    const int* __restrict__ counts, const int* __restrict__ offs,
    const int* __restrict__ pair_tok, const int* __restrict__ pair_rank,
    float* __restrict__ Yk)
{
  const int bid = blockIdx.x;
  const int dt  = bid >> 9;
  const int q   = bid & 511;
  const int xcd = q & 7;
  const int idx = q >> 3;
  const int e   = xcd * 2 + (idx & 1);
  const int mt  = idx >> 1;

  const int n_e = counts[e];
  const int m0  = mt * 128;
  if (m0 >= n_e) return;
  const int d0  = dt * 128;

  __shared__ short ldsA[3][128 * 32];
  __shared__ short ldsB[3][128 * 32];

  const int tid  = threadIdx.x;
  const int lane = tid & 63;
  const int wid  = tid >> 6;
  const int offs_e = offs[e];

  const short* srcA[2]; const short* srcB[2];
  #pragma unroll
  for (int i = 0; i < 2; ++i) {
    const int c    = wid * 2 + i;
    const int row  = 16 * c + (lane >> 2);
    const int slot = (lane & 3) ^ ((row >> 1) & 3);
    int r = m0 + row; if (r >= n_e) r = n_e - 1;
    srcA[i] = H + (size_t)(offs_e + r) * HIDP + slot * 8;
    srcB[i] = wdb + ((size_t)e * D_MODEL + d0 + row) * HIDP + slot * 8;
  }

  const int wm = wid >> 1, wn = wid & 1;
  const int fr = lane & 15, fs = lane >> 4;
  const int so = (fs ^ ((fr >> 1) & 3)) * 8;

  f32x4 acc[4][4];
  #pragma unroll
  for (int fi = 0; fi < 4; ++fi)
    #pragma unroll
    for (int fj = 0; fj < 4; ++fj) acc[fi][fj] = f32x4{0.f, 0.f, 0.f, 0.f};

  auto stage = [&](int kt, int b) {       // 4 vmem ops / thread
    const int ko = kt * 32;
    #pragma unroll
    for (int i = 0; i < 2; ++i) {
      gload16(srcA[i] + ko, &ldsA[b][(wid * 2 + i) * 512]);
      gload16(srcB[i] + ko, &ldsB[b][(wid * 2 + i) * 512]);
    }
  };

  auto compute = [&](int b) {
    const short* Ab = ldsA[b]; const short* Bb = ldsB[b];
    bf16x8 af[4], bb[4];
    #pragma unroll
    for (int fi = 0; fi < 4; ++fi)
      af[fi] = *(const bf16x8*)&Ab[(wm * 64 + fi * 16 + fr) * 32 + so];
    #pragma unroll
    for (int fj = 0; fj < 4; ++fj)
      bb[fj] = *(const bf16x8*)&Bb[(wn * 64 + fj * 16 + fr) * 32 + so];
    #pragma unroll
    for (int fi = 0; fi < 4; ++fi)
      #pragma unroll
      for (int fj = 0; fj < 4; ++fj)
        acc[fi][fj] = __builtin_amdgcn_mfma_f32_16x16x32_bf16(af[fi], bb[fj], acc[fi][fj], 0, 0, 0);
  };

  const int KT = HIDP / 32;  // 22
  stage(0, 0);
  stage(1, 1);
  int cur = 0, tgt = 2;
  for (int kt = 0; kt < KT; ++kt) {
    __builtin_amdgcn_s_barrier();
    __builtin_amdgcn_sched_barrier(0);
    if (kt + 2 < KT) stage(kt + 2, tgt);
    if (kt + 2 < KT)      { VMCNT(8); }
    else if (kt + 1 < KT) { VMCNT(4); }
    else                  { VMCNT(0); }
    __builtin_amdgcn_s_barrier();
    __builtin_amdgcn_sched_barrier(0);
    compute(cur);
    cur = (cur == 2) ? 0 : cur + 1;
    tgt = (tgt == 2) ? 0 : tgt + 1;
  }

  #pragma unroll
  for (int fi = 0; fi < 4; ++fi)
    #pragma unroll
    for (int j = 0; j < 4; ++j) {
      const int r = m0 + wm * 64 + fi * 16 + fs * 4 + j;
      if (r < n_e) {
        const int tok = pair_tok[e * NTOK + r];
        const int rk  = pair_rank[e * NTOK + r];
        float* yr = Yk + ((size_t)rk * NTOK + tok) * D_MODEL + d0 + wn * 64 + fr;
        #pragma unroll
        for (int fj = 0; fj < 4; ++fj)
          yr[fj * 16] = acc[fi][fj][j];
      }
    }
}

__global__ __launch_bounds__(256) void reduce_y_kernel(const float* __restrict__ Yk,
                                                       float* __restrict__ y) {
  const size_t i = ((size_t)blockIdx.x * 256 + threadIdx.x) * 4;
  const size_t P = (size_t)NTOK * D_MODEL;
  f32x4 s = *(const f32x4*)(Yk + i);
  s += *(const f32x4*)(Yk + P + i);
  s += *(const f32x4*)(Yk + 2 * P + i);
  s += *(const f32x4*)(Yk + 3 * P + i);
  *(f32x4*)(y + i) = s;
}

// ================================================================ stage 2 (atomic fallback, simple drain loop)
__global__ __launch_bounds__(256, 4) void stage2a_kernel(
    const short* __restrict__ H, const short* __restrict__ wdb,
    const int* __restrict__ counts, const int* __restrict__ offs,
    const int* __restrict__ pair_tok, float* __restrict__ y)
{
  const int bid = blockIdx.x;
  const int dt  = bid >> 9;
  const int q   = bid & 511;
  const int xcd = q & 7;
  const int idx = q >> 3;
  const int e   = xcd * 2 + (idx & 1);
  const int mt  = idx >> 1;

  const int n_e = counts[e];
  const int m0  = mt * 128;
  if (m0 >= n_e) return;
  const int d0  = dt * 128;

  __shared__ short ldsA[2][128 * 32];
  __shared__ short ldsB[2][128 * 32];

  const int tid  = threadIdx.x;
  const int lane = tid & 63;
  const int wid  = tid >> 6;
  const int offs_e = offs[e];

  const short* srcA[2]; const short* srcB[2];
  #pragma unroll
  for (int i = 0; i < 2; ++i) {
    const int c    = wid * 2 + i;
    const int row  = 16 * c + (lane >> 2);
    const int slot = (lane & 3) ^ ((row >> 1) & 3);
    int r = m0 + row; if (r >= n_e) r = n_e - 1;
    srcA[i] = H + (size_t)(offs_e + r) * HIDP + slot * 8;
    srcB[i] = wdb + ((size_t)e * D_MODEL + d0 + row) * HIDP + slot * 8;
  }

  const int wm = wid >> 1, wn = wid & 1;
  const int fr = lane & 15, fs = lane >> 4;
  const int so = (fs ^ ((fr >> 1) & 3)) * 8;

  f32x4 acc[4][4];
  #pragma unroll
  for (int fi = 0; fi < 4; ++fi)
    #pragma unroll
    for (int fj = 0; fj < 4; ++fj) acc[fi][fj] = f32x4{0.f, 0.f, 0.f, 0.f};

  auto stage = [&](int kt, int b) {
    const int ko = kt * 32;
    #pragma unroll
    for (int i = 0; i < 2; ++i) {
      gload16(srcA[i] + ko, &ldsA[b][(wid * 2 + i) * 512]);
      gload16(srcB[i] + ko, &ldsB[b][(wid * 2 + i) * 512]);
    }
  };

  auto compute = [&](int b) {
    const short* Ab = ldsA[b]; const short* Bb = ldsB[b];
    bf16x8 af[4], bb[4];
    #pragma unroll
    for (int fi = 0; fi < 4; ++fi)
      af[fi] = *(const bf16x8*)&Ab[(wm * 64 + fi * 16 + fr) * 32 + so];
    #pragma unroll
    for (int fj = 0; fj < 4; ++fj)
      bb[fj] = *(const bf16x8*)&Bb[(wn * 64 + fj * 16 + fr) * 32 + so];
    #pragma unroll
    for (int fi = 0; fi < 4; ++fi)
      #pragma unroll
      for (int fj = 0; fj < 4; ++fj)
        acc[fi][fj] = __builtin_amdgcn_mfma_f32_16x16x32_bf16(af[fi], bb[fj], acc[fi][fj], 0, 0, 0);
  };

  const int KT = HIDP / 32;
  stage(0, 0);
  for (int kt = 0; kt < KT; ++kt) {
    const int cur = kt & 1;
    __syncthreads();
    if (kt + 1 < KT) stage(kt + 1, cur ^ 1);
    compute(cur);
  }

  #pragma unroll
  for (int fi = 0; fi < 4; ++fi)
    #pragma unroll
    for (int j = 0; j < 4; ++j) {
      const int r = m0 + wm * 64 + fi * 16 + fs * 4 + j;
      if (r < n_e) {
        const int tok = pair_tok[e * NTOK + r];
        float* yr = y + (size_t)tok * D_MODEL + d0 + wn * 64 + fr;
        #pragma unroll
        for (int fj = 0; fj < 4; ++fj)
          atomicAdd(yr + fj * 16, acc[fi][fj][j]);
      }
    }
}

// ---------------------------------------------------------------- launch
extern "C" void kernel_launch(void* const* d_in, const int* in_sizes, int n_in,
                              void* d_out, int out_size, void* d_ws, size_t ws_size,
                              hipStream_t stream) {
  const float* x     = (const float*)d_in[0];
  const float* wgate = (const float*)d_in[1];
  const float* w_g   = (const float*)d_in[2];
  const float* w_u   = (const float*)d_in[3];
  const float* w_d   = (const float*)d_in[4];

  float* y        = (float*)d_out;
  float* loss_out = y + (size_t)NTOK * D_MODEL;

  char* ws = (char*)d_ws;
  int*   counts     = (int*)ws;
  int*   offs       = counts + 16;
  float* importance = (float*)(counts + 32);
  int*   pair_tok   = (int*)(ws + 256);
  float* pair_scr   = (float*)(ws + 256 + (size_t)NEXP * NTOK * 4);
  int*   pair_rank  = (int*)(ws + 256 + (size_t)2 * NEXP * NTOK * 4);
  short* H          = (short*)(ws + 256 + (size_t)3 * NEXP * NTOK * 4);

  const size_t H_BYTES = (size_t)NTOK * NSEL * HIDP * 2;
  short* xbuf = (short*)((char*)H + H_BYTES);
  short* wgb  = xbuf + (size_t)NTOK * D_MODEL;
  short* wub  = wgb + (size_t)NEXP * HIDP * D_MODEL;
  short* wdb  = wub + (size_t)NEXP * HIDP * D_MODEL;
  float* Yk   = (float*)(wdb + (size_t)NEXP * HIDP * D_MODEL);

  const size_t NEED_STORE = ((char*)(Yk + (size_t)NSEL * NTOK * D_MODEL)) - ws;
  const bool store_path = ws_size >= NEED_STORE;

  hipLaunchKernelGGL(zero_meta_kernel, dim3(1), dim3(64), 0, stream, counts, importance);
  hipLaunchKernelGGL(gate_kernel, dim3(NTOK), dim3(256), 0, stream,
                     x, wgate, counts, importance, pair_tok, pair_scr, pair_rank, xbuf);
  hipLaunchKernelGGL(scan_loss_kernel, dim3(1), dim3(64), 0, stream,
                     counts, importance, offs, loss_out);

  hipLaunchKernelGGL(conv_wgu_kernel, dim3(4096), dim3(256), 0, stream, w_g, w_u, wgb, wub);
  hipLaunchKernelGGL(conv_wd_kernel,  dim3(4096), dim3(256), 0, stream, w_d, wdb);
  hipLaunchKernelGGL(stage1b_kernel, dim3(11 * 512), dim3(256), 0, stream,
                     xbuf, wgb, wub, counts, offs, pair_tok, pair_scr, H);

  if (store_path) {
    hipLaunchKernelGGL(stage2s_kernel, dim3(32 * 512), dim3(256), 0, stream,
                       H, wdb, counts, offs, pair_tok, pair_rank, Yk);
    hipLaunchKernelGGL(reduce_y_kernel, dim3(NTOK * D_MODEL / 4 / 256), dim3(256), 0, stream,
                       Yk, y);
  } else {
    hipLaunchKernelGGL(zero_y_kernel, dim3(16384), dim3(256), 0, stream, y);
    hipLaunchKernelGGL(stage2a_kernel, dim3(32 * 512), dim3(256), 0, stream,
                       H, wdb, counts, offs, pair_tok, y);
  }
}